// Round 9
// baseline (365.224 us; speedup 1.0000x reference)
//
#include <hip/hip_runtime.h>

#define N_NODES 50000
#define NBUCK 782        // ceil(N_NODES / 64) -- 64 dst-nodes per bucket
#define BCAP 2048        // slots per bucket (mean fill 1024 + pad <=448)
#define BSHIFT 11

typedef __attribute__((ext_vector_type(8))) short short8;
typedef __attribute__((ext_vector_type(4))) float floatx4;
typedef __attribute__((ext_vector_type(2))) float floatx2;
typedef __attribute__((ext_vector_type(2))) int intx2;

static __device__ __forceinline__ unsigned short f2bf(float f) {
  unsigned int u = __builtin_bit_cast(unsigned int, f);
  u += 0x7fff + ((u >> 16) & 1);          // RNE
  return (unsigned short)(u >> 16);
}
// decode 8 fp8(e4m3) packed in int2 -> accumulate into 4x floatx2 (v_pk_add_f32)
static __device__ __forceinline__ void fp8x8_acc(intx2 v, floatx2* ac) {
  ac[0] += __builtin_amdgcn_cvt_pk_f32_fp8(v[0], false);
  ac[1] += __builtin_amdgcn_cvt_pk_f32_fp8(v[0], true);
  ac[2] += __builtin_amdgcn_cvt_pk_f32_fp8(v[1], false);
  ac[3] += __builtin_amdgcn_cvt_pk_f32_fp8(v[1], true);
}

// ---------------- K1: prep (casts incl. fp8 copy + zero sentinel rows) + bucket scatter ----------------

__global__ void __launch_bounds__(512) prep_scatter(
    const float* __restrict__ x,
    const float* __restrict__ Wl1, const float* __restrict__ Wr1,
    const float* __restrict__ Wl2, const float* __restrict__ Wr2,
    unsigned short* __restrict__ xb, unsigned char* __restrict__ xq,
    unsigned short* __restrict__ W1, unsigned short* __restrict__ W2,
    const int* __restrict__ src, const int* __restrict__ dst,
    int* __restrict__ bucket_cur, int* __restrict__ buf, int E, int n) {
  const int t = threadIdx.x;
  const int gid = blockIdx.x * 512 + t;
  const int gsz = gridDim.x * 512;
  for (int i = gid; i < n * 16; i += gsz) {       // 4 elems per iter
    float4 v = ((const float4*)x)[i];
    unsigned int lo = (unsigned int)f2bf(v.x) | ((unsigned int)f2bf(v.y) << 16);
    unsigned int hi = (unsigned int)f2bf(v.z) | ((unsigned int)f2bf(v.w) << 16);
    ((uint2*)xb)[i] = make_uint2(lo, hi);
    int q = __builtin_amdgcn_cvt_pk_fp8_f32(v.x, v.y, 0, false);
    q = __builtin_amdgcn_cvt_pk_fp8_f32(v.z, v.w, q, true);
    ((int*)xq)[i] = q;
  }
  // zero sentinel rows (index n): xq row n (64 B), h1q row n (128 B)
  {
    unsigned char* h1q = xq + ((size_t)n + 1) * 64;
    if (gid < 16) ((int*)(xq + (size_t)n * 64))[gid] = 0;
    if (gid >= 16 && gid < 48) ((int*)(h1q + (size_t)n * 128))[gid - 16] = 0;
  }
  for (int i = gid; i < 128 * 128; i += gsz) {
    int c = i >> 7, k = i & 127;
    W1[i] = f2bf(k < 64 ? Wl1[c * 64 + k] : Wr1[c * 64 + k - 64]);
  }
  for (int i = gid; i < 128 * 256; i += gsz) {
    int c = i >> 8, k = i & 255;
    W2[i] = f2bf(k < 128 ? Wl2[c * 128 + k] : Wr2[c * 128 + k - 128]);
  }

  // scatter: block handles chunk of 4096 edges; packed = (src<<6)|(dst&63)
  __shared__ int hist[NBUCK];
  __shared__ int base_s[NBUCK];
  for (int i = t; i < NBUCK; i += 512) hist[i] = 0;
  __syncthreads();
  int e0 = blockIdx.x * 4096;
  int sv[8], dv[8], bv[8];
#pragma unroll
  for (int p = 0; p < 8; ++p) {
    int e = e0 + p * 512 + t;
    if (e < E) {
      sv[p] = src[e];
      dv[p] = dst[e];
      bv[p] = dv[p] >> 6;
      atomicAdd(&hist[bv[p]], 1);
    } else bv[p] = -1;
  }
  __syncthreads();
  for (int i = t; i < NBUCK; i += 512) {
    int c = hist[i];
    base_s[i] = c > 0 ? atomicAdd(&bucket_cur[i], c) : 0;
  }
  __syncthreads();
  for (int i = t; i < NBUCK; i += 512) hist[i] = 0;   // reuse as sub-cursor
  __syncthreads();
#pragma unroll
  for (int p = 0; p < 8; ++p) {
    if (bv[p] >= 0) {
      int sub = base_s[bv[p]] + atomicAdd(&hist[bv[p]], 1);
      if (sub < BCAP) buf[(bv[p] << BSHIFT) + sub] = (sv[p] << 6) | (dv[p] & 63);
    }
  }
}

// ---------------- K2: bucket CSR (padded) + fp8 agg64 (2-deep prefetch) + layer-1 MFMA GEMM ----------------

__global__ void __launch_bounds__(512, 6) csr_agg_gemm1(
    int* __restrict__ buf, const int* __restrict__ bucket_cur,
    int* __restrict__ row_start, int* __restrict__ row_cnt,
    const unsigned short* __restrict__ xb, const unsigned char* __restrict__ xq,
    const unsigned short* __restrict__ W1, const float* __restrict__ b1,
    unsigned short* __restrict__ h1, unsigned char* __restrict__ h1q, int n) {
  __shared__ int eb[BCAP];                            // 8 KB staged packed edges
  __shared__ int gsrc[BCAP];                          // 8 KB grouped src lists
  __shared__ __align__(16) unsigned short aggS[64 * 72];  // 9 KB agg tile
  __shared__ int cnt[64];
  __shared__ int tmp[64];
  __shared__ int cur[64];
  const int t = threadIdx.x;
  const int b = blockIdx.x;
  const int node0 = b << 6;
  const int len = min(bucket_cur[b], BCAP);
  int* reg = buf + (b << BSHIFT);

  // --- CSR build (prefix over counts padded to multiple of 8) ---
  if (t < 64) cnt[t] = 0;
  __syncthreads();
  for (int i = t; i < len; i += 512) {
    int p = reg[i];
    eb[i] = p;
    atomicAdd(&cnt[p & 63], 1);
  }
  __syncthreads();
  if (t < 64) tmp[t] = (cnt[t] + 7) & ~7;
  __syncthreads();
#pragma unroll
  for (int off = 1; off < 64; off <<= 1) {
    int u = (t >= off && t < 64) ? tmp[t - off] : 0;
    __syncthreads();
    if (t < 64) tmp[t] += u;
    __syncthreads();
  }
  if (t < 64) {
    int c8 = (cnt[t] + 7) & ~7;
    int ex = tmp[t] - c8;
    cur[t] = ex;
    int nd = node0 + t;
    if (nd < n) {
      row_start[nd] = (b << BSHIFT) + ex;
      row_cnt[nd] = cnt[t];
    }
  }
  __syncthreads();
  for (int i = t; i < len; i += 512) {
    int p = eb[i];
    int sub = atomicAdd(&cur[p & 63], 1);
    int s = p >> 6;
    if (sub < BCAP) { gsrc[sub] = s; reg[sub] = s; }   // LDS + global copies
  }
  __syncthreads();
  if (t < 64) {                       // pad tail of each list with sentinel n
    int c8 = (cnt[t] + 7) & ~7;
    int e1 = tmp[t];
    for (int j = e1 - c8 + cnt[t]; j < e1; ++j)
      if (j < BCAP) { gsrc[j] = n; reg[j] = n; }
  }
  __syncthreads();

  // --- fp8 agg64: 8 waves, 2 nodes each, 2-deep prefetch (16 edges/node in flight) ---
  const int lane = t & 63;
  const int wv = t >> 6;
  const int eq = lane >> 3;            // edge slot 0..7
  const int cl = lane & 7;             // 8-B chunk: cols cl*8..cl*8+7
#pragma unroll 1
  for (int p = 0; p < 4; ++p) {
    int locA = wv + p * 16;
    int locB = locA + 8;
    int cnA = cnt[locA], cnB = cnt[locB];
    int cpA = (cnA + 7) & ~7, cpB = (cnB + 7) & ~7;
    int baseA = tmp[locA] - cpA;
    int baseB = tmp[locB] - cpB;
    floatx2 aA[4], aB[4];
#pragma unroll
    for (int j = 0; j < 4; ++j) { aA[j] = (floatx2){0.f, 0.f}; aB[j] = (floatx2){0.f, 0.f}; }
    int mx = max(cpA, cpB);
    int sA = (0 < cpA) ? gsrc[baseA + eq] : n;
    int sB = (0 < cpB) ? gsrc[baseB + eq] : n;
    int sA1 = (8 < cpA) ? gsrc[baseA + 8 + eq] : n;
    int sB1 = (8 < cpB) ? gsrc[baseB + 8 + eq] : n;
    intx2 vA = *(const intx2*)(xq + (size_t)sA * 64 + cl * 8);
    intx2 vB = *(const intx2*)(xq + (size_t)sB * 64 + cl * 8);
    intx2 uA = *(const intx2*)(xq + (size_t)sA1 * 64 + cl * 8);
    intx2 uB = *(const intx2*)(xq + (size_t)sB1 * 64 + cl * 8);
    for (int e = 16; e < mx; e += 8) {
      int nA = (e < cpA) ? gsrc[baseA + e + eq] : n;
      int nB = (e < cpB) ? gsrc[baseB + e + eq] : n;
      intx2 wA = *(const intx2*)(xq + (size_t)nA * 64 + cl * 8);
      intx2 wB = *(const intx2*)(xq + (size_t)nB * 64 + cl * 8);
      fp8x8_acc(vA, aA);
      fp8x8_acc(vB, aB);
      vA = uA; vB = uB; uA = wA; uB = wB;
    }
    fp8x8_acc(vA, aA);
    fp8x8_acc(vB, aB);
    fp8x8_acc(uA, aA);
    fp8x8_acc(uB, aB);
    float rA[8], rB[8];
#pragma unroll
    for (int j = 0; j < 4; ++j) {
      rA[2 * j] = aA[j][0]; rA[2 * j + 1] = aA[j][1];
      rB[2 * j] = aB[j][0]; rB[2 * j + 1] = aB[j][1];
    }
#pragma unroll
    for (int j = 0; j < 8; ++j) {
      rA[j] += __shfl_xor(rA[j], 8, 64);
      rA[j] += __shfl_xor(rA[j], 16, 64);
      rA[j] += __shfl_xor(rA[j], 32, 64);
      rB[j] += __shfl_xor(rB[j], 8, 64);
      rB[j] += __shfl_xor(rB[j], 16, 64);
      rB[j] += __shfl_xor(rB[j], 32, 64);
    }
    if (eq == 0) {
      float invA = 1.0f / (float)max(cnA, 1);
      float invB = 1.0f / (float)max(cnB, 1);
      short8 oA, oB;
#pragma unroll
      for (int j = 0; j < 8; ++j) { oA[j] = (short)f2bf(rA[j] * invA); oB[j] = (short)f2bf(rB[j] * invB); }
      *(short8*)(aggS + locA * 72 + cl * 8) = oA;
      *(short8*)(aggS + locB * 72 + cl * 8) = oB;
    }
  }
  __syncthreads();

  // --- MFMA gemm1: 8 waves = 2 row-tiles x 4 col-tiles of 32x32; K=128 ---
  const int m = lane & 15;
  const int q = lane >> 4;
  const int rw = (wv & 1) * 32;
  const int cw = (wv >> 1) * 32;
  floatx4 acc[2][2];
#pragma unroll
  for (int rt = 0; rt < 2; ++rt)
#pragma unroll
    for (int ct = 0; ct < 2; ++ct) acc[rt][ct] = (floatx4){0.f, 0.f, 0.f, 0.f};

  int ra = node0 + rw + m;      if (ra > n - 1) ra = n - 1;
  int rb = node0 + rw + 16 + m; if (rb > n - 1) rb = n - 1;
  const unsigned short* selfA0 = xb + (size_t)ra * 64 + q * 8;
  const unsigned short* selfA1 = xb + (size_t)rb * 64 + q * 8;
  const unsigned short* aggL0 = aggS + (rw + m) * 72 + q * 8;
  const unsigned short* aggL1 = aggS + (rw + 16 + m) * 72 + q * 8;
  const unsigned short* Wc0 = W1 + (size_t)(cw + m) * 128 + q * 8;
  const unsigned short* Wc1 = W1 + (size_t)(cw + 16 + m) * 128 + q * 8;

#pragma unroll
  for (int kc = 0; kc < 2; ++kc) {     // agg half: k 0..63
    short8 a0 = *(const short8*)(aggL0 + kc * 32);
    short8 a1 = *(const short8*)(aggL1 + kc * 32);
    short8 w0 = *(const short8*)(Wc0 + kc * 32);
    short8 w1 = *(const short8*)(Wc1 + kc * 32);
    acc[0][0] = __builtin_amdgcn_mfma_f32_16x16x32_bf16(a0, w0, acc[0][0], 0, 0, 0);
    acc[0][1] = __builtin_amdgcn_mfma_f32_16x16x32_bf16(a0, w1, acc[0][1], 0, 0, 0);
    acc[1][0] = __builtin_amdgcn_mfma_f32_16x16x32_bf16(a1, w0, acc[1][0], 0, 0, 0);
    acc[1][1] = __builtin_amdgcn_mfma_f32_16x16x32_bf16(a1, w1, acc[1][1], 0, 0, 0);
  }
#pragma unroll
  for (int kc = 0; kc < 2; ++kc) {     // self half: k 64..127
    short8 a0 = *(const short8*)(selfA0 + kc * 32);
    short8 a1 = *(const short8*)(selfA1 + kc * 32);
    short8 w0 = *(const short8*)(Wc0 + 64 + kc * 32);
    short8 w1 = *(const short8*)(Wc1 + 64 + kc * 32);
    acc[0][0] = __builtin_amdgcn_mfma_f32_16x16x32_bf16(a0, w0, acc[0][0], 0, 0, 0);
    acc[0][1] = __builtin_amdgcn_mfma_f32_16x16x32_bf16(a0, w1, acc[0][1], 0, 0, 0);
    acc[1][0] = __builtin_amdgcn_mfma_f32_16x16x32_bf16(a1, w0, acc[1][0], 0, 0, 0);
    acc[1][1] = __builtin_amdgcn_mfma_f32_16x16x32_bf16(a1, w1, acc[1][1], 0, 0, 0);
  }

  float bv0 = b1[cw + m], bv1 = b1[cw + 16 + m];
#pragma unroll
  for (int rt = 0; rt < 2; ++rt) {
#pragma unroll
    for (int j = 0; j < 4; ++j) {
      int row = node0 + rw + rt * 16 + q * 4 + j;
      if (row < n) {
        float v0 = acc[rt][0][j] + bv0; v0 = v0 > 0.f ? v0 : 0.f;
        float v1 = acc[rt][1][j] + bv1; v1 = v1 > 0.f ? v1 : 0.f;
        h1[(size_t)row * 128 + cw + m] = f2bf(v0);
        h1[(size_t)row * 128 + cw + 16 + m] = f2bf(v1);
        h1q[(size_t)row * 128 + cw + m] =
            (unsigned char)__builtin_amdgcn_cvt_pk_fp8_f32(v0, v0, 0, false);
        h1q[(size_t)row * 128 + cw + 16 + m] =
            (unsigned char)__builtin_amdgcn_cvt_pk_fp8_f32(v1, v1, 0, false);
      }
    }
  }
}

// ---------------- K3: fp8 agg128 (LDS metadata + 2-deep prefetch) + layer-2 MFMA GEMM ----------------

__global__ void __launch_bounds__(512, 6) agg_gemm2(
    const unsigned short* __restrict__ h1, const unsigned char* __restrict__ h1q,
    const int* __restrict__ row_start, const int* __restrict__ row_cnt,
    const int* __restrict__ buf, const unsigned short* __restrict__ W2,
    const float* __restrict__ b2, float* __restrict__ out, int n) {
  __shared__ int gsrcS[BCAP];                             // 8 KB staged indices
  __shared__ __align__(16) unsigned short aggS[64 * 136]; // 17 KB (pad 128->136)
  __shared__ int cntS[64];
  __shared__ int stS[64];
  const int t = threadIdx.x;
  const int lane = t & 63;
  const int wv = t >> 6;
  const int node0 = blockIdx.x << 6;
  const int boff = blockIdx.x << BSHIFT;

  {
    const int4* b4 = (const int4*)(buf + ((size_t)blockIdx.x << BSHIFT));
    ((int4*)gsrcS)[t] = b4[t];
  }
  if (t < 64) {
    int nd = node0 + t;
    cntS[t] = (nd < n) ? row_cnt[nd] : 0;
    stS[t]  = (nd < n) ? (row_start[nd] - boff) : 0;
  }
  __syncthreads();

  const int eq = lane >> 4;            // edge slot 0..3
  const int cl = lane & 15;            // 8-B chunk: cols cl*8..cl*8+7
#pragma unroll 1
  for (int lp = 0; lp < 4; ++lp) {
    int locA = wv + lp * 16;
    int locB = locA + 8;
    int cnA = cntS[locA], stA = stS[locA];
    int cnB = cntS[locB], stB = stS[locB];
    int cpA = (cnA + 7) & ~7, cpB = (cnB + 7) & ~7;
    int mx = max(cpA, cpB);
    floatx2 aA[4], aB[4];
#pragma unroll
    for (int j = 0; j < 4; ++j) { aA[j] = (floatx2){0.f, 0.f}; aB[j] = (floatx2){0.f, 0.f}; }
    int iA0 = (0 < cpA) ? gsrcS[stA + eq] : n;
    int iA1 = (0 < cpA) ? gsrcS[stA + 4 + eq] : n;
    int iB0 = (0 < cpB) ? gsrcS[stB + eq] : n;
    int iB1 = (0 < cpB) ? gsrcS[stB + 4 + eq] : n;
    intx2 vA0 = *(const intx2*)(h1q + (size_t)iA0 * 128 + cl * 8);
    intx2 vA1 = *(const intx2*)(h1q + (size_t)iA1 * 128 + cl * 8);
    intx2 vB0 = *(const intx2*)(h1q + (size_t)iB0 * 128 + cl * 8);
    intx2 vB1 = *(const intx2*)(h1q + (size_t)iB1 * 128 + cl * 8);
    int jA0 = (8 < cpA) ? gsrcS[stA + 8 + eq] : n;
    int jA1 = (8 < cpA) ? gsrcS[stA + 12 + eq] : n;
    int jB0 = (8 < cpB) ? gsrcS[stB + 8 + eq] : n;
    int jB1 = (8 < cpB) ? gsrcS[stB + 12 + eq] : n;
    intx2 uA0 = *(const intx2*)(h1q + (size_t)jA0 * 128 + cl * 8);
    intx2 uA1 = *(const intx2*)(h1q + (size_t)jA1 * 128 + cl * 8);
    intx2 uB0 = *(const intx2*)(h1q + (size_t)jB0 * 128 + cl * 8);
    intx2 uB1 = *(const intx2*)(h1q + (size_t)jB1 * 128 + cl * 8);
    for (int e = 16; e < mx; e += 8) {
      int kA0 = (e < cpA) ? gsrcS[stA + e + eq] : n;
      int kA1 = (e < cpA) ? gsrcS[stA + e + 4 + eq] : n;
      int kB0 = (e < cpB) ? gsrcS[stB + e + eq] : n;
      int kB1 = (e < cpB) ? gsrcS[stB + e + 4 + eq] : n;
      intx2 wA0 = *(const intx2*)(h1q + (size_t)kA0 * 128 + cl * 8);
      intx2 wA1 = *(const intx2*)(h1q + (size_t)kA1 * 128 + cl * 8);
      intx2 wB0 = *(const intx2*)(h1q + (size_t)kB0 * 128 + cl * 8);
      intx2 wB1 = *(const intx2*)(h1q + (size_t)kB1 * 128 + cl * 8);
      fp8x8_acc(vA0, aA); fp8x8_acc(vA1, aA);
      fp8x8_acc(vB0, aB); fp8x8_acc(vB1, aB);
      vA0 = uA0; vA1 = uA1; vB0 = uB0; vB1 = uB1;
      uA0 = wA0; uA1 = wA1; uB0 = wB0; uB1 = wB1;
    }
    fp8x8_acc(vA0, aA); fp8x8_acc(vA1, aA);
    fp8x8_acc(vB0, aB); fp8x8_acc(vB1, aB);
    fp8x8_acc(uA0, aA); fp8x8_acc(uA1, aA);
    fp8x8_acc(uB0, aB); fp8x8_acc(uB1, aB);

    float rA[8], rB[8];
#pragma unroll
    for (int j = 0; j < 4; ++j) {
      rA[2 * j] = aA[j][0]; rA[2 * j + 1] = aA[j][1];
      rB[2 * j] = aB[j][0]; rB[2 * j + 1] = aB[j][1];
    }
#pragma unroll
    for (int j = 0; j < 8; ++j) {
      rA[j] += __shfl_xor(rA[j], 16, 64);
      rA[j] += __shfl_xor(rA[j], 32, 64);
      rB[j] += __shfl_xor(rB[j], 16, 64);
      rB[j] += __shfl_xor(rB[j], 32, 64);
    }
    if (eq == 0) {
      float invA = 1.0f / (float)max(cnA, 1);
      float invB = 1.0f / (float)max(cnB, 1);
      short8 oA, oB;
#pragma unroll
      for (int j = 0; j < 8; ++j) { oA[j] = (short)f2bf(rA[j] * invA); oB[j] = (short)f2bf(rB[j] * invB); }
      *(short8*)(aggS + locA * 136 + cl * 8) = oA;
      *(short8*)(aggS + locB * 136 + cl * 8) = oB;
    }
  }
  __syncthreads();

  // --- MFMA gemm2: 8 waves = 2 row-tiles x 4 col-tiles of 32x32; K=256 ---
  const int m = lane & 15;
  const int q = lane >> 4;
  const int rw = (wv & 1) * 32;
  const int cw = (wv >> 1) * 32;
  floatx4 acc[2][2];
#pragma unroll
  for (int rt = 0; rt < 2; ++rt)
#pragma unroll
    for (int ct = 0; ct < 2; ++ct) acc[rt][ct] = (floatx4){0.f, 0.f, 0.f, 0.f};

  int ra = node0 + rw + m;      if (ra > n - 1) ra = n - 1;
  int rb = node0 + rw + 16 + m; if (rb > n - 1) rb = n - 1;
  const unsigned short* selfA0 = h1 + (size_t)ra * 128 + q * 8;
  const unsigned short* selfA1 = h1 + (size_t)rb * 128 + q * 8;
  const unsigned short* aggL0 = aggS + (rw + m) * 136 + q * 8;
  const unsigned short* aggL1 = aggS + (rw + 16 + m) * 136 + q * 8;
  const unsigned short* Wc0 = W2 + (size_t)(cw + m) * 256 + q * 8;
  const unsigned short* Wc1 = W2 + (size_t)(cw + 16 + m) * 256 + q * 8;

#pragma unroll
  for (int kc = 0; kc < 4; ++kc) {     // agg half: k 0..127
    short8 a0 = *(const short8*)(aggL0 + kc * 32);
    short8 a1 = *(const short8*)(aggL1 + kc * 32);
    short8 w0 = *(const short8*)(Wc0 + kc * 32);
    short8 w1 = *(const short8*)(Wc1 + kc * 32);
    acc[0][0] = __builtin_amdgcn_mfma_f32_16x16x32_bf16(a0, w0, acc[0][0], 0, 0, 0);
    acc[0][1] = __builtin_amdgcn_mfma_f32_16x16x32_bf16(a0, w1, acc[0][1], 0, 0, 0);
    acc[1][0] = __builtin_amdgcn_mfma_f32_16x16x32_bf16(a1, w0, acc[1][0], 0, 0, 0);
    acc[1][1] = __builtin_amdgcn_mfma_f32_16x16x32_bf16(a1, w1, acc[1][1], 0, 0, 0);
  }
#pragma unroll
  for (int kc = 0; kc < 4; ++kc) {     // self half: k 128..255
    short8 a0 = *(const short8*)(selfA0 + kc * 32);
    short8 a1 = *(const short8*)(selfA1 + kc * 32);
    short8 w0 = *(const short8*)(Wc0 + 128 + kc * 32);
    short8 w1 = *(const short8*)(Wc1 + 128 + kc * 32);
    acc[0][0] = __builtin_amdgcn_mfma_f32_16x16x32_bf16(a0, w0, acc[0][0], 0, 0, 0);
    acc[0][1] = __builtin_amdgcn_mfma_f32_16x16x32_bf16(a0, w1, acc[0][1], 0, 0, 0);
    acc[1][0] = __builtin_amdgcn_mfma_f32_16x16x32_bf16(a1, w0, acc[1][0], 0, 0, 0);
    acc[1][1] = __builtin_amdgcn_mfma_f32_16x16x32_bf16(a1, w1, acc[1][1], 0, 0, 0);
  }

  float bv0 = b2[cw + m], bv1 = b2[cw + 16 + m];
#pragma unroll
  for (int rt = 0; rt < 2; ++rt) {
#pragma unroll
    for (int j = 0; j < 4; ++j) {
      int row = node0 + rw + rt * 16 + q * 4 + j;
      if (row < n) {
        float v0 = acc[rt][0][j] + bv0; v0 = v0 > 0.f ? v0 : 0.f;
        float v1 = acc[rt][1][j] + bv1; v1 = v1 > 0.f ? v1 : 0.f;
        out[(size_t)row * 128 + cw + m] = v0;
        out[(size_t)row * 128 + cw + 16 + m] = v1;
      }
    }
  }
}

// ---------------- D1: diagnostic — agg_gemm2's gather+decode ONLY, x2 repeats ----------------
// Runs after 'out' is final; writes to dead scratch (h1 region). Per-rep chunk XOR
// prevents load CSE; the final data-dependent store keeps everything live.

__global__ void __launch_bounds__(512, 6) diag_gather(
    const unsigned char* __restrict__ h1q,
    const int* __restrict__ row_start, const int* __restrict__ row_cnt,
    const int* __restrict__ buf, float* __restrict__ scratch, int n) {
  __shared__ int gsrcS[BCAP];
  __shared__ int cntS[64];
  __shared__ int stS[64];
  const int t = threadIdx.x;
  const int lane = t & 63;
  const int wv = t >> 6;
  const int node0 = blockIdx.x << 6;
  const int boff = blockIdx.x << BSHIFT;
  {
    const int4* b4 = (const int4*)(buf + ((size_t)blockIdx.x << BSHIFT));
    ((int4*)gsrcS)[t] = b4[t];
  }
  if (t < 64) {
    int nd = node0 + t;
    cntS[t] = (nd < n) ? row_cnt[nd] : 0;
    stS[t]  = (nd < n) ? (row_start[nd] - boff) : 0;
  }
  __syncthreads();
  const int eq = lane >> 4;
  const int cl = lane & 15;
  floatx2 aA[4], aB[4];
#pragma unroll
  for (int j = 0; j < 4; ++j) { aA[j] = (floatx2){0.f, 0.f}; aB[j] = (floatx2){0.f, 0.f}; }
#pragma unroll 1
  for (int rep = 0; rep < 2; ++rep) {
    const int co = ((cl ^ (rep << 3)) & 15) * 8;      // rep-varying chunk: no CSE
#pragma unroll 1
    for (int lp = 0; lp < 4; ++lp) {
      int locA = wv + lp * 16;
      int locB = locA + 8;
      int cnA = cntS[locA], stA = stS[locA];
      int cnB = cntS[locB], stB = stS[locB];
      int cpA = (cnA + 7) & ~7, cpB = (cnB + 7) & ~7;
      int mx = max(cpA, cpB);
      int iA0 = (0 < cpA) ? gsrcS[stA + eq] : n;
      int iA1 = (0 < cpA) ? gsrcS[stA + 4 + eq] : n;
      int iB0 = (0 < cpB) ? gsrcS[stB + eq] : n;
      int iB1 = (0 < cpB) ? gsrcS[stB + 4 + eq] : n;
      intx2 vA0 = *(const intx2*)(h1q + (size_t)iA0 * 128 + co);
      intx2 vA1 = *(const intx2*)(h1q + (size_t)iA1 * 128 + co);
      intx2 vB0 = *(const intx2*)(h1q + (size_t)iB0 * 128 + co);
      intx2 vB1 = *(const intx2*)(h1q + (size_t)iB1 * 128 + co);
      int jA0 = (8 < cpA) ? gsrcS[stA + 8 + eq] : n;
      int jA1 = (8 < cpA) ? gsrcS[stA + 12 + eq] : n;
      int jB0 = (8 < cpB) ? gsrcS[stB + 8 + eq] : n;
      int jB1 = (8 < cpB) ? gsrcS[stB + 12 + eq] : n;
      intx2 uA0 = *(const intx2*)(h1q + (size_t)jA0 * 128 + co);
      intx2 uA1 = *(const intx2*)(h1q + (size_t)jA1 * 128 + co);
      intx2 uB0 = *(const intx2*)(h1q + (size_t)jB0 * 128 + co);
      intx2 uB1 = *(const intx2*)(h1q + (size_t)jB1 * 128 + co);
      for (int e = 16; e < mx; e += 8) {
        int kA0 = (e < cpA) ? gsrcS[stA + e + eq] : n;
        int kA1 = (e < cpA) ? gsrcS[stA + e + 4 + eq] : n;
        int kB0 = (e < cpB) ? gsrcS[stB + e + eq] : n;
        int kB1 = (e < cpB) ? gsrcS[stB + e + 4 + eq] : n;
        intx2 wA0 = *(const intx2*)(h1q + (size_t)kA0 * 128 + co);
        intx2 wA1 = *(const intx2*)(h1q + (size_t)kA1 * 128 + co);
        intx2 wB0 = *(const intx2*)(h1q + (size_t)kB0 * 128 + co);
        intx2 wB1 = *(const intx2*)(h1q + (size_t)kB1 * 128 + co);
        fp8x8_acc(vA0, aA); fp8x8_acc(vA1, aA);
        fp8x8_acc(vB0, aB); fp8x8_acc(vB1, aB);
        vA0 = uA0; vA1 = uA1; vB0 = uB0; vB1 = uB1;
        uA0 = wA0; uA1 = wA1; uB0 = wB0; uB1 = wB1;
      }
      fp8x8_acc(vA0, aA); fp8x8_acc(vA1, aA);
      fp8x8_acc(vB0, aB); fp8x8_acc(vB1, aB);
      fp8x8_acc(uA0, aA); fp8x8_acc(uA1, aA);
      fp8x8_acc(uB0, aB); fp8x8_acc(uB1, aB);
    }
  }
  float s = 0.f;
#pragma unroll
  for (int j = 0; j < 4; ++j) s += aA[j][0] + aA[j][1] + aB[j][0] + aB[j][1];
  scratch[blockIdx.x * 512 + t] = s;
}

// ---------------- D2: diagnostic — agg_gemm2 WITHOUT the gather (synth values), x4 repeats ----------------
// Same control flow, LDS index reads, reduce, aggS, MFMA, epilogue; values derived
// from indices arithmetically. Stores go to dead scratch with rep-varying indices.

__global__ void __launch_bounds__(512, 6) diag_nogather(
    const unsigned short* __restrict__ h1,
    const int* __restrict__ row_start, const int* __restrict__ row_cnt,
    const int* __restrict__ buf, const unsigned short* __restrict__ W2,
    const float* __restrict__ b2, float* __restrict__ scratch, int n) {
  __shared__ int gsrcS[BCAP];
  __shared__ __align__(16) unsigned short aggS[64 * 136];
  __shared__ int cntS[64];
  __shared__ int stS[64];
  const int t = threadIdx.x;
  const int lane = t & 63;
  const int wv = t >> 6;
  const int node0 = blockIdx.x << 6;
  const int boff = blockIdx.x << BSHIFT;
  {
    const int4* b4 = (const int4*)(buf + ((size_t)blockIdx.x << BSHIFT));
    ((int4*)gsrcS)[t] = b4[t];
  }
  if (t < 64) {
    int nd = node0 + t;
    cntS[t] = (nd < n) ? row_cnt[nd] : 0;
    stS[t]  = (nd < n) ? (row_start[nd] - boff) : 0;
  }
  __syncthreads();
  const int eq = lane >> 4;
  const int cl = lane & 15;
  const int m = lane & 15;
  const int q = lane >> 4;
  const int rw = (wv & 1) * 32;
  const int cw = (wv >> 1) * 32;
  floatx4 acc[2][2];
#pragma unroll
  for (int rt = 0; rt < 2; ++rt)
#pragma unroll
    for (int ct = 0; ct < 2; ++ct) acc[rt][ct] = (floatx4){0.f, 0.f, 0.f, 0.f};

#pragma unroll 1
  for (int rep = 0; rep < 4; ++rep) {
#pragma unroll 1
    for (int lp = 0; lp < 4; ++lp) {
      int locA = wv + lp * 16;
      int locB = locA + 8;
      int cnA = cntS[locA], stA = stS[locA];
      int cnB = cntS[locB], stB = stS[locB];
      int cpA = (cnA + 7) & ~7, cpB = (cnB + 7) & ~7;
      int mx = max(cpA, cpB);
      floatx2 aA[4], aB[4];
#pragma unroll
      for (int j = 0; j < 4; ++j) { aA[j] = (floatx2){0.f, 0.f}; aB[j] = (floatx2){0.f, 0.f}; }
      for (int e = 0; e < mx; e += 8) {
        int kA0 = (e < cpA) ? gsrcS[stA + e + eq] : n;
        int kA1 = (e < cpA) ? gsrcS[stA + e + 4 + eq] : n;
        int kB0 = (e < cpB) ? gsrcS[stB + e + eq] : n;
        int kB1 = (e < cpB) ? gsrcS[stB + e + 4 + eq] : n;
        intx2 wA0, wA1, wB0, wB1;          // synthesized (no global load)
        wA0[0] = kA0 * 0x9E3779B9 + rep; wA0[1] = kA0 ^ 0x5bd1e995;
        wA1[0] = kA1 * 0x9E3779B9 + rep; wA1[1] = kA1 ^ 0x5bd1e995;
        wB0[0] = kB0 * 0x9E3779B9 + rep; wB0[1] = kB0 ^ 0x5bd1e995;
        wB1[0] = kB1 * 0x9E3779B9 + rep; wB1[1] = kB1 ^ 0x5bd1e995;
        fp8x8_acc(wA0, aA); fp8x8_acc(wA1, aA);
        fp8x8_acc(wB0, aB); fp8x8_acc(wB1, aB);
      }
      float rA[8], rB[8];
#pragma unroll
      for (int j = 0; j < 4; ++j) {
        rA[2 * j] = aA[j][0]; rA[2 * j + 1] = aA[j][1];
        rB[2 * j] = aB[j][0]; rB[2 * j + 1] = aB[j][1];
      }
#pragma unroll
      for (int j = 0; j < 8; ++j) {
        rA[j] += __shfl_xor(rA[j], 16, 64);
        rA[j] += __shfl_xor(rA[j], 32, 64);
        rB[j] += __shfl_xor(rB[j], 16, 64);
        rB[j] += __shfl_xor(rB[j], 32, 64);
      }
      if (eq == 0) {
        float invA = 1.0f / (float)max(cnA, 1);
        float invB = 1.0f / (float)max(cnB, 1);
        short8 oA, oB;
#pragma unroll
        for (int j = 0; j < 8; ++j) { oA[j] = (short)f2bf(rA[j] * invA); oB[j] = (short)f2bf(rB[j] * invB); }
        *(short8*)(aggS + locA * 136 + cl * 8) = oA;
        *(short8*)(aggS + locB * 136 + cl * 8) = oB;
      }
    }
    __syncthreads();

    {
      int ra = node0 + rw + m;      if (ra > n - 1) ra = n - 1;
      int rb = node0 + rw + 16 + m; if (rb > n - 1) rb = n - 1;
      const unsigned short* selfA0 = h1 + (size_t)ra * 128 + q * 8;
      const unsigned short* selfA1 = h1 + (size_t)rb * 128 + q * 8;
      const unsigned short* aggL0 = aggS + (rw + m) * 136 + q * 8;
      const unsigned short* aggL1 = aggS + (rw + 16 + m) * 136 + q * 8;
      const unsigned short* Wc0 = W2 + (size_t)(cw + m) * 256 + q * 8;
      const unsigned short* Wc1 = W2 + (size_t)(cw + 16 + m) * 256 + q * 8;
#pragma unroll
      for (int kc = 0; kc < 4; ++kc) {
        short8 a0 = *(const short8*)(aggL0 + kc * 32);
        short8 a1 = *(const short8*)(aggL1 + kc * 32);
        short8 w0 = *(const short8*)(Wc0 + kc * 32);
        short8 w1 = *(const short8*)(Wc1 + kc * 32);
        acc[0][0] = __builtin_amdgcn_mfma_f32_16x16x32_bf16(a0, w0, acc[0][0], 0, 0, 0);
        acc[0][1] = __builtin_amdgcn_mfma_f32_16x16x32_bf16(a0, w1, acc[0][1], 0, 0, 0);
        acc[1][0] = __builtin_amdgcn_mfma_f32_16x16x32_bf16(a1, w0, acc[1][0], 0, 0, 0);
        acc[1][1] = __builtin_amdgcn_mfma_f32_16x16x32_bf16(a1, w1, acc[1][1], 0, 0, 0);
      }
#pragma unroll
      for (int kc = 0; kc < 4; ++kc) {
        short8 a0 = *(const short8*)(selfA0 + kc * 32);
        short8 a1 = *(const short8*)(selfA1 + kc * 32);
        short8 w0 = *(const short8*)(Wc0 + 128 + kc * 32);
        short8 w1 = *(const short8*)(Wc1 + 128 + kc * 32);
        acc[0][0] = __builtin_amdgcn_mfma_f32_16x16x32_bf16(a0, w0, acc[0][0], 0, 0, 0);
        acc[0][1] = __builtin_amdgcn_mfma_f32_16x16x32_bf16(a0, w1, acc[0][1], 0, 0, 0);
        acc[1][0] = __builtin_amdgcn_mfma_f32_16x16x32_bf16(a1, w0, acc[1][0], 0, 0, 0);
        acc[1][1] = __builtin_amdgcn_mfma_f32_16x16x32_bf16(a1, w1, acc[1][1], 0, 0, 0);
      }
      float bv0 = b2[cw + m], bv1 = b2[cw + 16 + m];
#pragma unroll
      for (int rt = 0; rt < 2; ++rt) {
#pragma unroll
        for (int j = 0; j < 4; ++j) {
          int row = node0 + rw + rt * 16 + q * 4 + j;
          if (row < n) {
            float v0 = acc[rt][0][j] + bv0; v0 = v0 > 0.f ? v0 : 0.f;
            float v1 = acc[rt][1][j] + bv1; v1 = v1 > 0.f ? v1 : 0.f;
            unsigned int i0 = ((unsigned int)(row * 128 + cw + m) + rep * 131101u) & 0xFFFFFu;
            unsigned int i1 = ((unsigned int)(row * 128 + cw + 16 + m) + rep * 131101u) & 0xFFFFFu;
            scratch[i0] = v0;
            scratch[i1] = v1;
          }
        }
      }
    }
    __syncthreads();
  }
}

// ---------------- launch ----------------

extern "C" void kernel_launch(void* const* d_in, const int* in_sizes, int n_in,
                              void* d_out, int out_size, void* d_ws, size_t ws_size,
                              hipStream_t stream) {
  const int N = N_NODES;
  const int E = in_sizes[1] / 2;
  const float* x   = (const float*)d_in[0];
  const int*   src = (const int*)d_in[1];
  const int*   dst = src + E;
  const float* Wl1 = (const float*)d_in[2];
  const float* Wr1 = (const float*)d_in[3];
  const float* b1  = (const float*)d_in[4];
  const float* Wl2 = (const float*)d_in[5];
  const float* Wr2 = (const float*)d_in[6];
  const float* b2  = (const float*)d_in[7];
  float* out = (float*)d_out;

  // workspace (~36 MB)
  unsigned short* xb = (unsigned short*)d_ws;         // N*64 bf16 (x cast)
  unsigned short* h1 = xb + (size_t)N * 64;           // N*128 bf16 (layer-1 out)
  unsigned short* W1 = h1 + (size_t)N * 128;          // 128*128
  unsigned short* W2 = W1 + 128 * 128;                // 128*256
  int* row_start  = (int*)(W2 + 128 * 256);           // N
  int* row_cnt    = row_start + N;                    // N
  int* bucket_cur = row_cnt + N;                      // NBUCK (padded to 784)
  int* buf        = bucket_cur + 784;                 // NBUCK*BCAP ints (6.4 MB)
  unsigned char* xq  = (unsigned char*)(buf + (size_t)NBUCK * BCAP);  // (N+1)*64 fp8
  unsigned char* h1q = xq + ((size_t)N + 1) * 64;                     // (N+1)*128 fp8

  (void)hipMemsetAsync(bucket_cur, 0, NBUCK * sizeof(int), stream);
  int sb = (E + 4095) / 4096;                         // 196 blocks
  prep_scatter<<<sb, 512, 0, stream>>>(x, Wl1, Wr1, Wl2, Wr2, xb, xq, W1, W2,
                                       src, dst, bucket_cur, buf, E, N);
  csr_agg_gemm1<<<NBUCK, 512, 0, stream>>>(buf, bucket_cur, row_start, row_cnt,
                                           xb, xq, W1, b1, h1, h1q, N);
  agg_gemm2<<<NBUCK, 512, 0, stream>>>(h1, h1q, row_start, row_cnt, buf, W2, b2, out, N);

  // --- diagnostics (after 'out' is final; write only to dead scratch = h1 region) ---
  float* scratch = (float*)h1;
  diag_gather<<<NBUCK, 512, 0, stream>>>(h1q, row_start, row_cnt, buf, scratch, N);
  diag_nogather<<<NBUCK, 512, 0, stream>>>(h1, row_start, row_cnt, buf, W2, b2,
                                           scratch + (1 << 20), N);
}

// Round 12
// 205.054 us; speedup vs baseline: 1.7811x; 1.7811x over previous
//
#include <hip/hip_runtime.h>

#define N_NODES 50000
#define NBUCK 782        // ceil(N_NODES / 64) -- 64 dst-nodes per bucket
#define BCAP 2048        // slots per bucket (mean fill 1024 + pad <=448)
#define BSHIFT 11
#define PGRID 512        // persistent-ish grid for K2/K3 (2 blocks/CU)

typedef __attribute__((ext_vector_type(8))) short short8;
typedef __attribute__((ext_vector_type(4))) float floatx4;
typedef __attribute__((ext_vector_type(2))) float floatx2;
typedef __attribute__((ext_vector_type(2))) int intx2;

static __device__ __forceinline__ unsigned short f2bf(float f) {
  unsigned int u = __builtin_bit_cast(unsigned int, f);
  u += 0x7fff + ((u >> 16) & 1);          // RNE
  return (unsigned short)(u >> 16);
}
// decode 8 fp8(e4m3) packed in int2 -> accumulate into 4x floatx2 (v_pk_add_f32)
static __device__ __forceinline__ void fp8x8_acc(intx2 v, floatx2* ac) {
  ac[0] += __builtin_amdgcn_cvt_pk_f32_fp8(v[0], false);
  ac[1] += __builtin_amdgcn_cvt_pk_f32_fp8(v[0], true);
  ac[2] += __builtin_amdgcn_cvt_pk_f32_fp8(v[1], false);
  ac[3] += __builtin_amdgcn_cvt_pk_f32_fp8(v[1], true);
}

// ---------------- K1: prep (casts incl. fp8 copy + zero sentinel rows) + bucket scatter ----------------

__global__ void __launch_bounds__(512) prep_scatter(
    const float* __restrict__ x,
    const float* __restrict__ Wl1, const float* __restrict__ Wr1,
    const float* __restrict__ Wl2, const float* __restrict__ Wr2,
    unsigned short* __restrict__ xb, unsigned char* __restrict__ xq,
    unsigned short* __restrict__ W1, unsigned short* __restrict__ W2,
    const int* __restrict__ src, const int* __restrict__ dst,
    int* __restrict__ bucket_cur, int* __restrict__ buf, int E, int n) {
  const int t = threadIdx.x;
  const int gid = blockIdx.x * 512 + t;
  const int gsz = gridDim.x * 512;
  for (int i = gid; i < n * 16; i += gsz) {       // 4 elems per iter
    float4 v = ((const float4*)x)[i];
    unsigned int lo = (unsigned int)f2bf(v.x) | ((unsigned int)f2bf(v.y) << 16);
    unsigned int hi = (unsigned int)f2bf(v.z) | ((unsigned int)f2bf(v.w) << 16);
    ((uint2*)xb)[i] = make_uint2(lo, hi);
    int q = __builtin_amdgcn_cvt_pk_fp8_f32(v.x, v.y, 0, false);
    q = __builtin_amdgcn_cvt_pk_fp8_f32(v.z, v.w, q, true);
    ((int*)xq)[i] = q;
  }
  // zero sentinel rows (index n): xq row n (64 B), h1q row n (128 B)
  {
    unsigned char* h1q = xq + ((size_t)n + 1) * 64;
    if (gid < 16) ((int*)(xq + (size_t)n * 64))[gid] = 0;
    if (gid >= 16 && gid < 48) ((int*)(h1q + (size_t)n * 128))[gid - 16] = 0;
  }
  for (int i = gid; i < 128 * 128; i += gsz) {
    int c = i >> 7, k = i & 127;
    W1[i] = f2bf(k < 64 ? Wl1[c * 64 + k] : Wr1[c * 64 + k - 64]);
  }
  for (int i = gid; i < 128 * 256; i += gsz) {
    int c = i >> 8, k = i & 255;
    W2[i] = f2bf(k < 128 ? Wl2[c * 128 + k] : Wr2[c * 128 + k - 128]);
  }

  // scatter: block handles chunk of 4096 edges; packed = (src<<6)|(dst&63)
  __shared__ int hist[NBUCK];
  __shared__ int base_s[NBUCK];
  for (int i = t; i < NBUCK; i += 512) hist[i] = 0;
  __syncthreads();
  int e0 = blockIdx.x * 4096;
  int sv[8], dv[8], bv[8];
#pragma unroll
  for (int p = 0; p < 8; ++p) {
    int e = e0 + p * 512 + t;
    if (e < E) {
      sv[p] = src[e];
      dv[p] = dst[e];
      bv[p] = dv[p] >> 6;
      atomicAdd(&hist[bv[p]], 1);
    } else bv[p] = -1;
  }
  __syncthreads();
  for (int i = t; i < NBUCK; i += 512) {
    int c = hist[i];
    base_s[i] = c > 0 ? atomicAdd(&bucket_cur[i], c) : 0;
  }
  __syncthreads();
  for (int i = t; i < NBUCK; i += 512) hist[i] = 0;   // reuse as sub-cursor
  __syncthreads();
#pragma unroll
  for (int p = 0; p < 8; ++p) {
    if (bv[p] >= 0) {
      int sub = base_s[bv[p]] + atomicAdd(&hist[bv[p]], 1);
      if (sub < BCAP) buf[(bv[p] << BSHIFT) + sub] = (sv[p] << 6) | (dv[p] & 63);
    }
  }
}

// ---------------- K2: bucket CSR (padded) + fp8 agg64 + layer-1 MFMA GEMM ----------------
// Persistent-ish: PGRID blocks loop over buckets (1-2 each).

__global__ void __launch_bounds__(512, 6) csr_agg_gemm1(
    int* __restrict__ buf, const int* __restrict__ bucket_cur,
    int* __restrict__ row_start, int* __restrict__ row_cnt,
    const unsigned short* __restrict__ xb, const unsigned char* __restrict__ xq,
    const unsigned short* __restrict__ W1, const float* __restrict__ b1,
    unsigned short* __restrict__ h1, unsigned char* __restrict__ h1q, int n) {
  __shared__ int eb[BCAP];                            // 8 KB staged packed edges
  __shared__ int gsrc[BCAP];                          // 8 KB grouped src lists
  __shared__ __align__(16) unsigned short aggS[64 * 72];  // 9 KB agg tile
  __shared__ int cnt[64];
  __shared__ int tmp[64];
  __shared__ int cur[64];
  const int t = threadIdx.x;
  const int lane = t & 63;
  const int wv = t >> 6;

  for (int b = blockIdx.x; b < NBUCK; b += gridDim.x) {
    const int node0 = b << 6;
    const int len = min(bucket_cur[b], BCAP);
    int* reg = buf + (b << BSHIFT);

    // --- CSR build (prefix over counts padded to multiple of 8) ---
    if (t < 64) cnt[t] = 0;
    __syncthreads();
    for (int i = t; i < len; i += 512) {
      int p = reg[i];
      eb[i] = p;
      atomicAdd(&cnt[p & 63], 1);
    }
    __syncthreads();
    if (t < 64) tmp[t] = (cnt[t] + 7) & ~7;
    __syncthreads();
#pragma unroll
    for (int off = 1; off < 64; off <<= 1) {
      int u = (t >= off && t < 64) ? tmp[t - off] : 0;
      __syncthreads();
      if (t < 64) tmp[t] += u;
      __syncthreads();
    }
    if (t < 64) {
      int c8 = (cnt[t] + 7) & ~7;
      int ex = tmp[t] - c8;
      cur[t] = ex;
      int nd = node0 + t;
      if (nd < n) {
        row_start[nd] = (b << BSHIFT) + ex;
        row_cnt[nd] = cnt[t];
      }
    }
    __syncthreads();
    for (int i = t; i < len; i += 512) {
      int p = eb[i];
      int sub = atomicAdd(&cur[p & 63], 1);
      int s = p >> 6;
      if (sub < BCAP) { gsrc[sub] = s; reg[sub] = s; }   // LDS + global copies
    }
    __syncthreads();
    if (t < 64) {                       // pad tail of each list with sentinel n
      int c8 = (cnt[t] + 7) & ~7;
      int e1 = tmp[t];
      for (int j = e1 - c8 + cnt[t]; j < e1; ++j)
        if (j < BCAP) { gsrc[j] = n; reg[j] = n; }
    }
    __syncthreads();

    // --- fp8 agg64: 8 waves, 2 nodes each, 2-deep prefetch ---
    const int eq = lane >> 3;            // edge slot 0..7
    const int cl = lane & 7;             // 8-B chunk: cols cl*8..cl*8+7
#pragma unroll 1
    for (int p = 0; p < 4; ++p) {
      int locA = wv + p * 16;
      int locB = locA + 8;
      int cnA = cnt[locA], cnB = cnt[locB];
      int cpA = (cnA + 7) & ~7, cpB = (cnB + 7) & ~7;
      int baseA = tmp[locA] - cpA;
      int baseB = tmp[locB] - cpB;
      floatx2 aA[4], aB[4];
#pragma unroll
      for (int j = 0; j < 4; ++j) { aA[j] = (floatx2){0.f, 0.f}; aB[j] = (floatx2){0.f, 0.f}; }
      int mx = max(cpA, cpB);
      int sA = (0 < cpA) ? gsrc[baseA + eq] : n;
      int sB = (0 < cpB) ? gsrc[baseB + eq] : n;
      int sA1 = (8 < cpA) ? gsrc[baseA + 8 + eq] : n;
      int sB1 = (8 < cpB) ? gsrc[baseB + 8 + eq] : n;
      intx2 vA = *(const intx2*)(xq + (size_t)sA * 64 + cl * 8);
      intx2 vB = *(const intx2*)(xq + (size_t)sB * 64 + cl * 8);
      intx2 uA = *(const intx2*)(xq + (size_t)sA1 * 64 + cl * 8);
      intx2 uB = *(const intx2*)(xq + (size_t)sB1 * 64 + cl * 8);
      for (int e = 16; e < mx; e += 8) {
        int nA = (e < cpA) ? gsrc[baseA + e + eq] : n;
        int nB = (e < cpB) ? gsrc[baseB + e + eq] : n;
        intx2 wA = *(const intx2*)(xq + (size_t)nA * 64 + cl * 8);
        intx2 wB = *(const intx2*)(xq + (size_t)nB * 64 + cl * 8);
        fp8x8_acc(vA, aA);
        fp8x8_acc(vB, aB);
        vA = uA; vB = uB; uA = wA; uB = wB;
      }
      fp8x8_acc(vA, aA);
      fp8x8_acc(vB, aB);
      fp8x8_acc(uA, aA);
      fp8x8_acc(uB, aB);
      float rA[8], rB[8];
#pragma unroll
      for (int j = 0; j < 4; ++j) {
        rA[2 * j] = aA[j][0]; rA[2 * j + 1] = aA[j][1];
        rB[2 * j] = aB[j][0]; rB[2 * j + 1] = aB[j][1];
      }
#pragma unroll
      for (int j = 0; j < 8; ++j) {
        rA[j] += __shfl_xor(rA[j], 8, 64);
        rA[j] += __shfl_xor(rA[j], 16, 64);
        rA[j] += __shfl_xor(rA[j], 32, 64);
        rB[j] += __shfl_xor(rB[j], 8, 64);
        rB[j] += __shfl_xor(rB[j], 16, 64);
        rB[j] += __shfl_xor(rB[j], 32, 64);
      }
      if (eq == 0) {
        float invA = 1.0f / (float)max(cnA, 1);
        float invB = 1.0f / (float)max(cnB, 1);
        short8 oA, oB;
#pragma unroll
        for (int j = 0; j < 8; ++j) { oA[j] = (short)f2bf(rA[j] * invA); oB[j] = (short)f2bf(rB[j] * invB); }
        *(short8*)(aggS + locA * 72 + cl * 8) = oA;
        *(short8*)(aggS + locB * 72 + cl * 8) = oB;
      }
    }
    __syncthreads();

    // --- MFMA gemm1: 8 waves = 2 row-tiles x 4 col-tiles of 32x32; K=128 ---
    {
      const int m = lane & 15;
      const int q = lane >> 4;
      const int rw = (wv & 1) * 32;
      const int cw = (wv >> 1) * 32;
      floatx4 acc[2][2];
#pragma unroll
      for (int rt = 0; rt < 2; ++rt)
#pragma unroll
        for (int ct = 0; ct < 2; ++ct) acc[rt][ct] = (floatx4){0.f, 0.f, 0.f, 0.f};

      int ra = node0 + rw + m;      if (ra > n - 1) ra = n - 1;
      int rb = node0 + rw + 16 + m; if (rb > n - 1) rb = n - 1;
      const unsigned short* selfA0 = xb + (size_t)ra * 64 + q * 8;
      const unsigned short* selfA1 = xb + (size_t)rb * 64 + q * 8;
      const unsigned short* aggL0 = aggS + (rw + m) * 72 + q * 8;
      const unsigned short* aggL1 = aggS + (rw + 16 + m) * 72 + q * 8;
      const unsigned short* Wc0 = W1 + (size_t)(cw + m) * 128 + q * 8;
      const unsigned short* Wc1 = W1 + (size_t)(cw + 16 + m) * 128 + q * 8;

#pragma unroll
      for (int kc = 0; kc < 2; ++kc) {   // agg half: k 0..63
        short8 a0 = *(const short8*)(aggL0 + kc * 32);
        short8 a1 = *(const short8*)(aggL1 + kc * 32);
        short8 w0 = *(const short8*)(Wc0 + kc * 32);
        short8 w1 = *(const short8*)(Wc1 + kc * 32);
        acc[0][0] = __builtin_amdgcn_mfma_f32_16x16x32_bf16(a0, w0, acc[0][0], 0, 0, 0);
        acc[0][1] = __builtin_amdgcn_mfma_f32_16x16x32_bf16(a0, w1, acc[0][1], 0, 0, 0);
        acc[1][0] = __builtin_amdgcn_mfma_f32_16x16x32_bf16(a1, w0, acc[1][0], 0, 0, 0);
        acc[1][1] = __builtin_amdgcn_mfma_f32_16x16x32_bf16(a1, w1, acc[1][1], 0, 0, 0);
      }
#pragma unroll
      for (int kc = 0; kc < 2; ++kc) {   // self half: k 64..127
        short8 a0 = *(const short8*)(selfA0 + kc * 32);
        short8 a1 = *(const short8*)(selfA1 + kc * 32);
        short8 w0 = *(const short8*)(Wc0 + 64 + kc * 32);
        short8 w1 = *(const short8*)(Wc1 + 64 + kc * 32);
        acc[0][0] = __builtin_amdgcn_mfma_f32_16x16x32_bf16(a0, w0, acc[0][0], 0, 0, 0);
        acc[0][1] = __builtin_amdgcn_mfma_f32_16x16x32_bf16(a0, w1, acc[0][1], 0, 0, 0);
        acc[1][0] = __builtin_amdgcn_mfma_f32_16x16x32_bf16(a1, w0, acc[1][0], 0, 0, 0);
        acc[1][1] = __builtin_amdgcn_mfma_f32_16x16x32_bf16(a1, w1, acc[1][1], 0, 0, 0);
      }

      float bv0 = b1[cw + m], bv1 = b1[cw + 16 + m];
#pragma unroll
      for (int rt = 0; rt < 2; ++rt) {
#pragma unroll
        for (int j = 0; j < 4; ++j) {
          int row = node0 + rw + rt * 16 + q * 4 + j;
          if (row < n) {
            float v0 = acc[rt][0][j] + bv0; v0 = v0 > 0.f ? v0 : 0.f;
            float v1 = acc[rt][1][j] + bv1; v1 = v1 > 0.f ? v1 : 0.f;
            h1[(size_t)row * 128 + cw + m] = f2bf(v0);
            h1[(size_t)row * 128 + cw + 16 + m] = f2bf(v1);
            h1q[(size_t)row * 128 + cw + m] =
                (unsigned char)__builtin_amdgcn_cvt_pk_fp8_f32(v0, v0, 0, false);
            h1q[(size_t)row * 128 + cw + 16 + m] =
                (unsigned char)__builtin_amdgcn_cvt_pk_fp8_f32(v1, v1, 0, false);
          }
        }
      }
    }
    __syncthreads();
  }
}

// ---------------- K3: fp8 agg128 (LDS metadata + 2-deep prefetch) + layer-2 MFMA GEMM ----------------
// Persistent-ish: PGRID blocks loop over buckets (1-2 each).

__global__ void __launch_bounds__(512, 6) agg_gemm2(
    const unsigned short* __restrict__ h1, const unsigned char* __restrict__ h1q,
    const int* __restrict__ row_start, const int* __restrict__ row_cnt,
    const int* __restrict__ buf, const unsigned short* __restrict__ W2,
    const float* __restrict__ b2, float* __restrict__ out, int n) {
  __shared__ int gsrcS[BCAP];                             // 8 KB staged indices
  __shared__ __align__(16) unsigned short aggS[64 * 136]; // 17 KB (pad 128->136)
  __shared__ int cntS[64];
  __shared__ int stS[64];
  const int t = threadIdx.x;
  const int lane = t & 63;
  const int wv = t >> 6;

  for (int b = blockIdx.x; b < NBUCK; b += gridDim.x) {
    const int node0 = b << 6;
    const int boff = b << BSHIFT;

    __syncthreads();                    // all threads done with prior bucket's LDS
    {
      const int4* b4 = (const int4*)(buf + ((size_t)b << BSHIFT));
      ((int4*)gsrcS)[t] = b4[t];
    }
    if (t < 64) {
      int nd = node0 + t;
      cntS[t] = (nd < n) ? row_cnt[nd] : 0;
      stS[t]  = (nd < n) ? (row_start[nd] - boff) : 0;
    }
    __syncthreads();

    const int eq = lane >> 4;            // edge slot 0..3
    const int cl = lane & 15;            // 8-B chunk: cols cl*8..cl*8+7
#pragma unroll 1
    for (int lp = 0; lp < 4; ++lp) {
      int locA = wv + lp * 16;
      int locB = locA + 8;
      int cnA = cntS[locA], stA = stS[locA];
      int cnB = cntS[locB], stB = stS[locB];
      int cpA = (cnA + 7) & ~7, cpB = (cnB + 7) & ~7;
      int mx = max(cpA, cpB);
      floatx2 aA[4], aB[4];
#pragma unroll
      for (int j = 0; j < 4; ++j) { aA[j] = (floatx2){0.f, 0.f}; aB[j] = (floatx2){0.f, 0.f}; }
      int iA0 = (0 < cpA) ? gsrcS[stA + eq] : n;
      int iA1 = (0 < cpA) ? gsrcS[stA + 4 + eq] : n;
      int iB0 = (0 < cpB) ? gsrcS[stB + eq] : n;
      int iB1 = (0 < cpB) ? gsrcS[stB + 4 + eq] : n;
      intx2 vA0 = *(const intx2*)(h1q + (size_t)iA0 * 128 + cl * 8);
      intx2 vA1 = *(const intx2*)(h1q + (size_t)iA1 * 128 + cl * 8);
      intx2 vB0 = *(const intx2*)(h1q + (size_t)iB0 * 128 + cl * 8);
      intx2 vB1 = *(const intx2*)(h1q + (size_t)iB1 * 128 + cl * 8);
      int jA0 = (8 < cpA) ? gsrcS[stA + 8 + eq] : n;
      int jA1 = (8 < cpA) ? gsrcS[stA + 12 + eq] : n;
      int jB0 = (8 < cpB) ? gsrcS[stB + 8 + eq] : n;
      int jB1 = (8 < cpB) ? gsrcS[stB + 12 + eq] : n;
      intx2 uA0 = *(const intx2*)(h1q + (size_t)jA0 * 128 + cl * 8);
      intx2 uA1 = *(const intx2*)(h1q + (size_t)jA1 * 128 + cl * 8);
      intx2 uB0 = *(const intx2*)(h1q + (size_t)jB0 * 128 + cl * 8);
      intx2 uB1 = *(const intx2*)(h1q + (size_t)jB1 * 128 + cl * 8);
      for (int e = 16; e < mx; e += 8) {
        int kA0 = (e < cpA) ? gsrcS[stA + e + eq] : n;
        int kA1 = (e < cpA) ? gsrcS[stA + e + 4 + eq] : n;
        int kB0 = (e < cpB) ? gsrcS[stB + e + eq] : n;
        int kB1 = (e < cpB) ? gsrcS[stB + e + 4 + eq] : n;
        intx2 wA0 = *(const intx2*)(h1q + (size_t)kA0 * 128 + cl * 8);
        intx2 wA1 = *(const intx2*)(h1q + (size_t)kA1 * 128 + cl * 8);
        intx2 wB0 = *(const intx2*)(h1q + (size_t)kB0 * 128 + cl * 8);
        intx2 wB1 = *(const intx2*)(h1q + (size_t)kB1 * 128 + cl * 8);
        fp8x8_acc(vA0, aA); fp8x8_acc(vA1, aA);
        fp8x8_acc(vB0, aB); fp8x8_acc(vB1, aB);
        vA0 = uA0; vA1 = uA1; vB0 = uB0; vB1 = uB1;
        uA0 = wA0; uA1 = wA1; uB0 = wB0; uB1 = wB1;
      }
      fp8x8_acc(vA0, aA); fp8x8_acc(vA1, aA);
      fp8x8_acc(vB0, aB); fp8x8_acc(vB1, aB);
      fp8x8_acc(uA0, aA); fp8x8_acc(uA1, aA);
      fp8x8_acc(uB0, aB); fp8x8_acc(uB1, aB);

      float rA[8], rB[8];
#pragma unroll
      for (int j = 0; j < 4; ++j) {
        rA[2 * j] = aA[j][0]; rA[2 * j + 1] = aA[j][1];
        rB[2 * j] = aB[j][0]; rB[2 * j + 1] = aB[j][1];
      }
#pragma unroll
      for (int j = 0; j < 8; ++j) {
        rA[j] += __shfl_xor(rA[j], 16, 64);
        rA[j] += __shfl_xor(rA[j], 32, 64);
        rB[j] += __shfl_xor(rB[j], 16, 64);
        rB[j] += __shfl_xor(rB[j], 32, 64);
      }
      if (eq == 0) {
        float invA = 1.0f / (float)max(cnA, 1);
        float invB = 1.0f / (float)max(cnB, 1);
        short8 oA, oB;
#pragma unroll
        for (int j = 0; j < 8; ++j) { oA[j] = (short)f2bf(rA[j] * invA); oB[j] = (short)f2bf(rB[j] * invB); }
        *(short8*)(aggS + locA * 136 + cl * 8) = oA;
        *(short8*)(aggS + locB * 136 + cl * 8) = oB;
      }
    }
    __syncthreads();

    // --- MFMA gemm2: 8 waves = 2 row-tiles x 4 col-tiles of 32x32; K=256 ---
    {
      const int m = lane & 15;
      const int q = lane >> 4;
      const int rw = (wv & 1) * 32;
      const int cw = (wv >> 1) * 32;
      floatx4 acc[2][2];
#pragma unroll
      for (int rt = 0; rt < 2; ++rt)
#pragma unroll
        for (int ct = 0; ct < 2; ++ct) acc[rt][ct] = (floatx4){0.f, 0.f, 0.f, 0.f};

      int ra = node0 + rw + m;      if (ra > n - 1) ra = n - 1;
      int rb = node0 + rw + 16 + m; if (rb > n - 1) rb = n - 1;
      const unsigned short* selfA0 = h1 + (size_t)ra * 128 + q * 8;
      const unsigned short* selfA1 = h1 + (size_t)rb * 128 + q * 8;
      const unsigned short* aggL0 = aggS + (rw + m) * 136 + q * 8;
      const unsigned short* aggL1 = aggS + (rw + 16 + m) * 136 + q * 8;
      const unsigned short* Wc0 = W2 + (size_t)(cw + m) * 256 + q * 8;
      const unsigned short* Wc1 = W2 + (size_t)(cw + 16 + m) * 256 + q * 8;

#pragma unroll
      for (int kc = 0; kc < 4; ++kc) {   // agg half: k 0..127
        short8 a0 = *(const short8*)(aggL0 + kc * 32);
        short8 a1 = *(const short8*)(aggL1 + kc * 32);
        short8 w0 = *(const short8*)(Wc0 + kc * 32);
        short8 w1 = *(const short8*)(Wc1 + kc * 32);
        acc[0][0] = __builtin_amdgcn_mfma_f32_16x16x32_bf16(a0, w0, acc[0][0], 0, 0, 0);
        acc[0][1] = __builtin_amdgcn_mfma_f32_16x16x32_bf16(a0, w1, acc[0][1], 0, 0, 0);
        acc[1][0] = __builtin_amdgcn_mfma_f32_16x16x32_bf16(a1, w0, acc[1][0], 0, 0, 0);
        acc[1][1] = __builtin_amdgcn_mfma_f32_16x16x32_bf16(a1, w1, acc[1][1], 0, 0, 0);
      }
#pragma unroll
      for (int kc = 0; kc < 4; ++kc) {   // self half: k 128..255
        short8 a0 = *(const short8*)(selfA0 + kc * 32);
        short8 a1 = *(const short8*)(selfA1 + kc * 32);
        short8 w0 = *(const short8*)(Wc0 + 128 + kc * 32);
        short8 w1 = *(const short8*)(Wc1 + 128 + kc * 32);
        acc[0][0] = __builtin_amdgcn_mfma_f32_16x16x32_bf16(a0, w0, acc[0][0], 0, 0, 0);
        acc[0][1] = __builtin_amdgcn_mfma_f32_16x16x32_bf16(a0, w1, acc[0][1], 0, 0, 0);
        acc[1][0] = __builtin_amdgcn_mfma_f32_16x16x32_bf16(a1, w0, acc[1][0], 0, 0, 0);
        acc[1][1] = __builtin_amdgcn_mfma_f32_16x16x32_bf16(a1, w1, acc[1][1], 0, 0, 0);
      }

      float bv0 = b2[cw + m], bv1 = b2[cw + 16 + m];
#pragma unroll
      for (int rt = 0; rt < 2; ++rt) {
#pragma unroll
        for (int j = 0; j < 4; ++j) {
          int row = node0 + rw + rt * 16 + q * 4 + j;
          if (row < n) {
            float v0 = acc[rt][0][j] + bv0; v0 = v0 > 0.f ? v0 : 0.f;
            float v1 = acc[rt][1][j] + bv1; v1 = v1 > 0.f ? v1 : 0.f;
            out[(size_t)row * 128 + cw + m] = v0;
            out[(size_t)row * 128 + cw + 16 + m] = v1;
          }
        }
      }
    }
  }
}

// ---------------- launch ----------------

extern "C" void kernel_launch(void* const* d_in, const int* in_sizes, int n_in,
                              void* d_out, int out_size, void* d_ws, size_t ws_size,
                              hipStream_t stream) {
  const int N = N_NODES;
  const int E = in_sizes[1] / 2;
  const float* x   = (const float*)d_in[0];
  const int*   src = (const int*)d_in[1];
  const int*   dst = src + E;
  const float* Wl1 = (const float*)d_in[2];
  const float* Wr1 = (const float*)d_in[3];
  const float* b1  = (const float*)d_in[4];
  const float* Wl2 = (const float*)d_in[5];
  const float* Wr2 = (const float*)d_in[6];
  const float* b2  = (const float*)d_in[7];
  float* out = (float*)d_out;

  // workspace (~36 MB)
  unsigned short* xb = (unsigned short*)d_ws;         // N*64 bf16 (x cast)
  unsigned short* h1 = xb + (size_t)N * 64;           // N*128 bf16 (layer-1 out)
  unsigned short* W1 = h1 + (size_t)N * 128;          // 128*128
  unsigned short* W2 = W1 + 128 * 128;                // 128*256
  int* row_start  = (int*)(W2 + 128 * 256);           // N
  int* row_cnt    = row_start + N;                    // N
  int* bucket_cur = row_cnt + N;                      // NBUCK (padded to 784)
  int* buf        = bucket_cur + 784;                 // NBUCK*BCAP ints (6.4 MB)
  unsigned char* xq  = (unsigned char*)(buf + (size_t)NBUCK * BCAP);  // (N+1)*64 fp8
  unsigned char* h1q = xq + ((size_t)N + 1) * 64;                     // (N+1)*128 fp8

  (void)hipMemsetAsync(bucket_cur, 0, NBUCK * sizeof(int), stream);
  int sb = (E + 4095) / 4096;                         // 196 blocks
  prep_scatter<<<sb, 512, 0, stream>>>(x, Wl1, Wr1, Wl2, Wr2, xb, xq, W1, W2,
                                       src, dst, bucket_cur, buf, E, N);
  csr_agg_gemm1<<<PGRID, 512, 0, stream>>>(buf, bucket_cur, row_start, row_cnt,
                                           xb, xq, W1, b1, h1, h1q, N);
  agg_gemm2<<<PGRID, 512, 0, stream>>>(h1, h1q, row_start, row_cnt, buf, W2, b2, out, N);
}

// Round 13
// 200.016 us; speedup vs baseline: 1.8260x; 1.0252x over previous
//
#include <hip/hip_runtime.h>

#define N_NODES 50000
#define NBUCK 782        // ceil(N_NODES / 64) -- 64 dst-nodes per bucket
#define BCAP 2048        // slots per bucket (mean fill 1024 + pad <=448)
#define BSHIFT 11

typedef __attribute__((ext_vector_type(8))) short short8;
typedef __attribute__((ext_vector_type(4))) float floatx4;
typedef __attribute__((ext_vector_type(2))) float floatx2;
typedef __attribute__((ext_vector_type(2))) int intx2;

static __device__ __forceinline__ unsigned short f2bf(float f) {
  unsigned int u = __builtin_bit_cast(unsigned int, f);
  u += 0x7fff + ((u >> 16) & 1);          // RNE
  return (unsigned short)(u >> 16);
}
// decode 8 fp8(e4m3) packed in int2 -> accumulate into 4x floatx2 (v_pk_add_f32)
static __device__ __forceinline__ void fp8x8_acc(intx2 v, floatx2* ac) {
  ac[0] += __builtin_amdgcn_cvt_pk_f32_fp8(v[0], false);
  ac[1] += __builtin_amdgcn_cvt_pk_f32_fp8(v[0], true);
  ac[2] += __builtin_amdgcn_cvt_pk_f32_fp8(v[1], false);
  ac[3] += __builtin_amdgcn_cvt_pk_f32_fp8(v[1], true);
}

// ---------------- K1: prep (casts + sentinel zero) + bucket scatter ----------------
// Grid = 1024 blocks (2/CU): cast loops fully subscribed; scatter chunk = ceil(E/1024).

__global__ void __launch_bounds__(512) prep_scatter(
    const float* __restrict__ x,
    const float* __restrict__ Wl1, const float* __restrict__ Wr1,
    const float* __restrict__ Wl2, const float* __restrict__ Wr2,
    unsigned short* __restrict__ xb, unsigned char* __restrict__ xq,
    unsigned short* __restrict__ W1, unsigned short* __restrict__ W2,
    const int* __restrict__ src, const int* __restrict__ dst,
    int* __restrict__ bucket_cur, int* __restrict__ buf, int chunk, int E, int n) {
  const int t = threadIdx.x;
  const int gid = blockIdx.x * 512 + t;
  const int gsz = gridDim.x * 512;
  for (int i = gid; i < n * 16; i += gsz) {       // 4 elems per iter
    float4 v = ((const float4*)x)[i];
    unsigned int lo = (unsigned int)f2bf(v.x) | ((unsigned int)f2bf(v.y) << 16);
    unsigned int hi = (unsigned int)f2bf(v.z) | ((unsigned int)f2bf(v.w) << 16);
    ((uint2*)xb)[i] = make_uint2(lo, hi);
    int q = __builtin_amdgcn_cvt_pk_fp8_f32(v.x, v.y, 0, false);
    q = __builtin_amdgcn_cvt_pk_fp8_f32(v.z, v.w, q, true);
    ((int*)xq)[i] = q;
  }
  // zero sentinel rows (index n): xq row n (64 B), h1q row n (128 B)
  {
    unsigned char* h1q = xq + ((size_t)n + 1) * 64;
    if (gid < 16) ((int*)(xq + (size_t)n * 64))[gid] = 0;
    if (gid >= 16 && gid < 48) ((int*)(h1q + (size_t)n * 128))[gid - 16] = 0;
  }
  for (int i = gid; i < 128 * 128; i += gsz) {
    int c = i >> 7, k = i & 127;
    W1[i] = f2bf(k < 64 ? Wl1[c * 64 + k] : Wr1[c * 64 + k - 64]);
  }
  for (int i = gid; i < 128 * 256; i += gsz) {
    int c = i >> 8, k = i & 255;
    W2[i] = f2bf(k < 128 ? Wl2[c * 128 + k] : Wr2[c * 128 + k - 128]);
  }

  // scatter: block handles [e0, e1) of edges; packed = (src<<6)|(dst&63)
  __shared__ int hist[NBUCK];
  __shared__ int base_s[NBUCK];
  const int e0 = blockIdx.x * chunk;
  const int e1 = min(e0 + chunk, E);
  if (e0 >= E) return;
  for (int i = t; i < NBUCK; i += 512) hist[i] = 0;
  __syncthreads();
  for (int e = e0 + t; e < e1; e += 512)          // pass 1: histogram
    atomicAdd(&hist[dst[e] >> 6], 1);
  __syncthreads();
  for (int i = t; i < NBUCK; i += 512) {
    int c = hist[i];
    base_s[i] = c > 0 ? atomicAdd(&bucket_cur[i], c) : 0;
  }
  __syncthreads();
  for (int i = t; i < NBUCK; i += 512) hist[i] = 0;   // reuse as sub-cursor
  __syncthreads();
  for (int e = e0 + t; e < e1; e += 512) {        // pass 2: scatter
    int s = src[e], d = dst[e];
    int bk = d >> 6;
    int sub = base_s[bk] + atomicAdd(&hist[bk], 1);
    if (sub < BCAP) buf[(bk << BSHIFT) + sub] = (s << 6) | (d & 63);
  }
}

// ---------------- K2: bucket CSR (padded) + fp8 agg64 (2-deep prefetch) + layer-1 MFMA GEMM ----------------

__global__ void __launch_bounds__(512, 6) csr_agg_gemm1(
    int* __restrict__ buf, const int* __restrict__ bucket_cur,
    int* __restrict__ row_start, int* __restrict__ row_cnt,
    const unsigned short* __restrict__ xb, const unsigned char* __restrict__ xq,
    const unsigned short* __restrict__ W1, const float* __restrict__ b1,
    unsigned short* __restrict__ h1, unsigned char* __restrict__ h1q, int n) {
  __shared__ int eb[BCAP];                            // 8 KB staged packed edges
  __shared__ int gsrc[BCAP];                          // 8 KB grouped src lists
  __shared__ __align__(16) unsigned short aggS[64 * 72];  // 9 KB agg tile
  __shared__ int cnt[64];
  __shared__ int tmp[64];
  __shared__ int cur[64];
  const int t = threadIdx.x;
  const int b = blockIdx.x;
  const int node0 = b << 6;
  const int len = min(bucket_cur[b], BCAP);
  int* reg = buf + (b << BSHIFT);

  // --- CSR build (prefix over counts padded to multiple of 8) ---
  if (t < 64) cnt[t] = 0;
  __syncthreads();
  for (int i = t; i < len; i += 512) {
    int p = reg[i];
    eb[i] = p;
    atomicAdd(&cnt[p & 63], 1);
  }
  __syncthreads();
  if (t < 64) tmp[t] = (cnt[t] + 7) & ~7;
  __syncthreads();
#pragma unroll
  for (int off = 1; off < 64; off <<= 1) {
    int u = (t >= off && t < 64) ? tmp[t - off] : 0;
    __syncthreads();
    if (t < 64) tmp[t] += u;
    __syncthreads();
  }
  if (t < 64) {
    int c8 = (cnt[t] + 7) & ~7;
    int ex = tmp[t] - c8;
    cur[t] = ex;
    int nd = node0 + t;
    if (nd < n) {
      row_start[nd] = (b << BSHIFT) + ex;
      row_cnt[nd] = cnt[t];
    }
  }
  __syncthreads();
  for (int i = t; i < len; i += 512) {
    int p = eb[i];
    int sub = atomicAdd(&cur[p & 63], 1);
    int s = p >> 6;
    if (sub < BCAP) { gsrc[sub] = s; reg[sub] = s; }   // LDS + global copies
  }
  __syncthreads();
  if (t < 64) {                       // pad tail of each list with sentinel n
    int c8 = (cnt[t] + 7) & ~7;
    int e1 = tmp[t];
    for (int j = e1 - c8 + cnt[t]; j < e1; ++j)
      if (j < BCAP) { gsrc[j] = n; reg[j] = n; }
  }
  __syncthreads();

  // --- fp8 agg64: 8 waves, 2 nodes each, 2-deep prefetch (16 edges/node in flight) ---
  const int lane = t & 63;
  const int wv = t >> 6;
  const int eq = lane >> 3;            // edge slot 0..7
  const int cl = lane & 7;             // 8-B chunk: cols cl*8..cl*8+7
#pragma unroll 1
  for (int p = 0; p < 4; ++p) {
    int locA = wv + p * 16;
    int locB = locA + 8;
    int cnA = cnt[locA], cnB = cnt[locB];
    int cpA = (cnA + 7) & ~7, cpB = (cnB + 7) & ~7;
    int baseA = tmp[locA] - cpA;
    int baseB = tmp[locB] - cpB;
    floatx2 aA[4], aB[4];
#pragma unroll
    for (int j = 0; j < 4; ++j) { aA[j] = (floatx2){0.f, 0.f}; aB[j] = (floatx2){0.f, 0.f}; }
    int mx = max(cpA, cpB);
    int sA = (0 < cpA) ? gsrc[baseA + eq] : n;
    int sB = (0 < cpB) ? gsrc[baseB + eq] : n;
    int sA1 = (8 < cpA) ? gsrc[baseA + 8 + eq] : n;
    int sB1 = (8 < cpB) ? gsrc[baseB + 8 + eq] : n;
    intx2 vA = *(const intx2*)(xq + (size_t)sA * 64 + cl * 8);
    intx2 vB = *(const intx2*)(xq + (size_t)sB * 64 + cl * 8);
    intx2 uA = *(const intx2*)(xq + (size_t)sA1 * 64 + cl * 8);
    intx2 uB = *(const intx2*)(xq + (size_t)sB1 * 64 + cl * 8);
    for (int e = 16; e < mx; e += 8) {
      int nA = (e < cpA) ? gsrc[baseA + e + eq] : n;
      int nB = (e < cpB) ? gsrc[baseB + e + eq] : n;
      intx2 wA = *(const intx2*)(xq + (size_t)nA * 64 + cl * 8);
      intx2 wB = *(const intx2*)(xq + (size_t)nB * 64 + cl * 8);
      fp8x8_acc(vA, aA);
      fp8x8_acc(vB, aB);
      vA = uA; vB = uB; uA = wA; uB = wB;
    }
    fp8x8_acc(vA, aA);
    fp8x8_acc(vB, aB);
    fp8x8_acc(uA, aA);
    fp8x8_acc(uB, aB);
    float rA[8], rB[8];
#pragma unroll
    for (int j = 0; j < 4; ++j) {
      rA[2 * j] = aA[j][0]; rA[2 * j + 1] = aA[j][1];
      rB[2 * j] = aB[j][0]; rB[2 * j + 1] = aB[j][1];
    }
#pragma unroll
    for (int j = 0; j < 8; ++j) {
      rA[j] += __shfl_xor(rA[j], 8, 64);
      rA[j] += __shfl_xor(rA[j], 16, 64);
      rA[j] += __shfl_xor(rA[j], 32, 64);
      rB[j] += __shfl_xor(rB[j], 8, 64);
      rB[j] += __shfl_xor(rB[j], 16, 64);
      rB[j] += __shfl_xor(rB[j], 32, 64);
    }
    if (eq == 0) {
      float invA = 1.0f / (float)max(cnA, 1);
      float invB = 1.0f / (float)max(cnB, 1);
      short8 oA, oB;
#pragma unroll
      for (int j = 0; j < 8; ++j) { oA[j] = (short)f2bf(rA[j] * invA); oB[j] = (short)f2bf(rB[j] * invB); }
      *(short8*)(aggS + locA * 72 + cl * 8) = oA;
      *(short8*)(aggS + locB * 72 + cl * 8) = oB;
    }
  }
  __syncthreads();

  // --- MFMA gemm1: 8 waves = 2 row-tiles x 4 col-tiles of 32x32; K=128 ---
  const int m = lane & 15;
  const int q = lane >> 4;
  const int rw = (wv & 1) * 32;
  const int cw = (wv >> 1) * 32;
  floatx4 acc[2][2];
#pragma unroll
  for (int rt = 0; rt < 2; ++rt)
#pragma unroll
    for (int ct = 0; ct < 2; ++ct) acc[rt][ct] = (floatx4){0.f, 0.f, 0.f, 0.f};

  int ra = node0 + rw + m;      if (ra > n - 1) ra = n - 1;
  int rb = node0 + rw + 16 + m; if (rb > n - 1) rb = n - 1;
  const unsigned short* selfA0 = xb + (size_t)ra * 64 + q * 8;
  const unsigned short* selfA1 = xb + (size_t)rb * 64 + q * 8;
  const unsigned short* aggL0 = aggS + (rw + m) * 72 + q * 8;
  const unsigned short* aggL1 = aggS + (rw + 16 + m) * 72 + q * 8;
  const unsigned short* Wc0 = W1 + (size_t)(cw + m) * 128 + q * 8;
  const unsigned short* Wc1 = W1 + (size_t)(cw + 16 + m) * 128 + q * 8;

#pragma unroll
  for (int kc = 0; kc < 2; ++kc) {     // agg half: k 0..63
    short8 a0 = *(const short8*)(aggL0 + kc * 32);
    short8 a1 = *(const short8*)(aggL1 + kc * 32);
    short8 w0 = *(const short8*)(Wc0 + kc * 32);
    short8 w1 = *(const short8*)(Wc1 + kc * 32);
    acc[0][0] = __builtin_amdgcn_mfma_f32_16x16x32_bf16(a0, w0, acc[0][0], 0, 0, 0);
    acc[0][1] = __builtin_amdgcn_mfma_f32_16x16x32_bf16(a0, w1, acc[0][1], 0, 0, 0);
    acc[1][0] = __builtin_amdgcn_mfma_f32_16x16x32_bf16(a1, w0, acc[1][0], 0, 0, 0);
    acc[1][1] = __builtin_amdgcn_mfma_f32_16x16x32_bf16(a1, w1, acc[1][1], 0, 0, 0);
  }
#pragma unroll
  for (int kc = 0; kc < 2; ++kc) {     // self half: k 64..127
    short8 a0 = *(const short8*)(selfA0 + kc * 32);
    short8 a1 = *(const short8*)(selfA1 + kc * 32);
    short8 w0 = *(const short8*)(Wc0 + 64 + kc * 32);
    short8 w1 = *(const short8*)(Wc1 + 64 + kc * 32);
    acc[0][0] = __builtin_amdgcn_mfma_f32_16x16x32_bf16(a0, w0, acc[0][0], 0, 0, 0);
    acc[0][1] = __builtin_amdgcn_mfma_f32_16x16x32_bf16(a0, w1, acc[0][1], 0, 0, 0);
    acc[1][0] = __builtin_amdgcn_mfma_f32_16x16x32_bf16(a1, w0, acc[1][0], 0, 0, 0);
    acc[1][1] = __builtin_amdgcn_mfma_f32_16x16x32_bf16(a1, w1, acc[1][1], 0, 0, 0);
  }

  float bv0 = b1[cw + m], bv1 = b1[cw + 16 + m];
#pragma unroll
  for (int rt = 0; rt < 2; ++rt) {
#pragma unroll
    for (int j = 0; j < 4; ++j) {
      int row = node0 + rw + rt * 16 + q * 4 + j;
      if (row < n) {
        float v0 = acc[rt][0][j] + bv0; v0 = v0 > 0.f ? v0 : 0.f;
        float v1 = acc[rt][1][j] + bv1; v1 = v1 > 0.f ? v1 : 0.f;
        h1[(size_t)row * 128 + cw + m] = f2bf(v0);
        h1[(size_t)row * 128 + cw + 16 + m] = f2bf(v1);
        h1q[(size_t)row * 128 + cw + m] =
            (unsigned char)__builtin_amdgcn_cvt_pk_fp8_f32(v0, v0, 0, false);
        h1q[(size_t)row * 128 + cw + 16 + m] =
            (unsigned char)__builtin_amdgcn_cvt_pk_fp8_f32(v1, v1, 0, false);
      }
    }
  }
}

// ---------------- K3: fp8 agg128 (LDS metadata + 2-deep prefetch) + layer-2 MFMA GEMM ----------------

__global__ void __launch_bounds__(512, 6) agg_gemm2(
    const unsigned short* __restrict__ h1, const unsigned char* __restrict__ h1q,
    const int* __restrict__ row_start, const int* __restrict__ row_cnt,
    const int* __restrict__ buf, const unsigned short* __restrict__ W2,
    const float* __restrict__ b2, float* __restrict__ out, int n) {
  __shared__ int gsrcS[BCAP];                             // 8 KB staged indices
  __shared__ __align__(16) unsigned short aggS[64 * 136]; // 17 KB (pad 128->136)
  __shared__ int cntS[64];
  __shared__ int stS[64];
  const int t = threadIdx.x;
  const int lane = t & 63;
  const int wv = t >> 6;
  const int node0 = blockIdx.x << 6;
  const int boff = blockIdx.x << BSHIFT;

  {
    const int4* b4 = (const int4*)(buf + ((size_t)blockIdx.x << BSHIFT));
    ((int4*)gsrcS)[t] = b4[t];
  }
  if (t < 64) {
    int nd = node0 + t;
    cntS[t] = (nd < n) ? row_cnt[nd] : 0;
    stS[t]  = (nd < n) ? (row_start[nd] - boff) : 0;
  }
  __syncthreads();

  const int eq = lane >> 4;            // edge slot 0..3
  const int cl = lane & 15;            // 8-B chunk: cols cl*8..cl*8+7
#pragma unroll 1
  for (int lp = 0; lp < 4; ++lp) {
    int locA = wv + lp * 16;
    int locB = locA + 8;
    int cnA = cntS[locA], stA = stS[locA];
    int cnB = cntS[locB], stB = stS[locB];
    int cpA = (cnA + 7) & ~7, cpB = (cnB + 7) & ~7;
    int mx = max(cpA, cpB);
    floatx2 aA[4], aB[4];
#pragma unroll
    for (int j = 0; j < 4; ++j) { aA[j] = (floatx2){0.f, 0.f}; aB[j] = (floatx2){0.f, 0.f}; }
    int iA0 = (0 < cpA) ? gsrcS[stA + eq] : n;
    int iA1 = (0 < cpA) ? gsrcS[stA + 4 + eq] : n;
    int iB0 = (0 < cpB) ? gsrcS[stB + eq] : n;
    int iB1 = (0 < cpB) ? gsrcS[stB + 4 + eq] : n;
    intx2 vA0 = *(const intx2*)(h1q + (size_t)iA0 * 128 + cl * 8);
    intx2 vA1 = *(const intx2*)(h1q + (size_t)iA1 * 128 + cl * 8);
    intx2 vB0 = *(const intx2*)(h1q + (size_t)iB0 * 128 + cl * 8);
    intx2 vB1 = *(const intx2*)(h1q + (size_t)iB1 * 128 + cl * 8);
    int jA0 = (8 < cpA) ? gsrcS[stA + 8 + eq] : n;
    int jA1 = (8 < cpA) ? gsrcS[stA + 12 + eq] : n;
    int jB0 = (8 < cpB) ? gsrcS[stB + 8 + eq] : n;
    int jB1 = (8 < cpB) ? gsrcS[stB + 12 + eq] : n;
    intx2 uA0 = *(const intx2*)(h1q + (size_t)jA0 * 128 + cl * 8);
    intx2 uA1 = *(const intx2*)(h1q + (size_t)jA1 * 128 + cl * 8);
    intx2 uB0 = *(const intx2*)(h1q + (size_t)jB0 * 128 + cl * 8);
    intx2 uB1 = *(const intx2*)(h1q + (size_t)jB1 * 128 + cl * 8);
    for (int e = 16; e < mx; e += 8) {
      int kA0 = (e < cpA) ? gsrcS[stA + e + eq] : n;
      int kA1 = (e < cpA) ? gsrcS[stA + e + 4 + eq] : n;
      int kB0 = (e < cpB) ? gsrcS[stB + e + eq] : n;
      int kB1 = (e < cpB) ? gsrcS[stB + e + 4 + eq] : n;
      intx2 wA0 = *(const intx2*)(h1q + (size_t)kA0 * 128 + cl * 8);
      intx2 wA1 = *(const intx2*)(h1q + (size_t)kA1 * 128 + cl * 8);
      intx2 wB0 = *(const intx2*)(h1q + (size_t)kB0 * 128 + cl * 8);
      intx2 wB1 = *(const intx2*)(h1q + (size_t)kB1 * 128 + cl * 8);
      fp8x8_acc(vA0, aA); fp8x8_acc(vA1, aA);
      fp8x8_acc(vB0, aB); fp8x8_acc(vB1, aB);
      vA0 = uA0; vA1 = uA1; vB0 = uB0; vB1 = uB1;
      uA0 = wA0; uA1 = wA1; uB0 = wB0; uB1 = wB1;
    }
    fp8x8_acc(vA0, aA); fp8x8_acc(vA1, aA);
    fp8x8_acc(vB0, aB); fp8x8_acc(vB1, aB);
    fp8x8_acc(uA0, aA); fp8x8_acc(uA1, aA);
    fp8x8_acc(uB0, aB); fp8x8_acc(uB1, aB);

    float rA[8], rB[8];
#pragma unroll
    for (int j = 0; j < 4; ++j) {
      rA[2 * j] = aA[j][0]; rA[2 * j + 1] = aA[j][1];
      rB[2 * j] = aB[j][0]; rB[2 * j + 1] = aB[j][1];
    }
#pragma unroll
    for (int j = 0; j < 8; ++j) {
      rA[j] += __shfl_xor(rA[j], 16, 64);
      rA[j] += __shfl_xor(rA[j], 32, 64);
      rB[j] += __shfl_xor(rB[j], 16, 64);
      rB[j] += __shfl_xor(rB[j], 32, 64);
    }
    if (eq == 0) {
      float invA = 1.0f / (float)max(cnA, 1);
      float invB = 1.0f / (float)max(cnB, 1);
      short8 oA, oB;
#pragma unroll
      for (int j = 0; j < 8; ++j) { oA[j] = (short)f2bf(rA[j] * invA); oB[j] = (short)f2bf(rB[j] * invB); }
      *(short8*)(aggS + locA * 136 + cl * 8) = oA;
      *(short8*)(aggS + locB * 136 + cl * 8) = oB;
    }
  }
  __syncthreads();

  // --- MFMA gemm2: 8 waves = 2 row-tiles x 4 col-tiles of 32x32; K=256 ---
  const int m = lane & 15;
  const int q = lane >> 4;
  const int rw = (wv & 1) * 32;
  const int cw = (wv >> 1) * 32;
  floatx4 acc[2][2];
#pragma unroll
  for (int rt = 0; rt < 2; ++rt)
#pragma unroll
    for (int ct = 0; ct < 2; ++ct) acc[rt][ct] = (floatx4){0.f, 0.f, 0.f, 0.f};

  int ra = node0 + rw + m;      if (ra > n - 1) ra = n - 1;
  int rb = node0 + rw + 16 + m; if (rb > n - 1) rb = n - 1;
  const unsigned short* selfA0 = h1 + (size_t)ra * 128 + q * 8;
  const unsigned short* selfA1 = h1 + (size_t)rb * 128 + q * 8;
  const unsigned short* aggL0 = aggS + (rw + m) * 136 + q * 8;
  const unsigned short* aggL1 = aggS + (rw + 16 + m) * 136 + q * 8;
  const unsigned short* Wc0 = W2 + (size_t)(cw + m) * 256 + q * 8;
  const unsigned short* Wc1 = W2 + (size_t)(cw + 16 + m) * 256 + q * 8;

#pragma unroll
  for (int kc = 0; kc < 4; ++kc) {     // agg half: k 0..127
    short8 a0 = *(const short8*)(aggL0 + kc * 32);
    short8 a1 = *(const short8*)(aggL1 + kc * 32);
    short8 w0 = *(const short8*)(Wc0 + kc * 32);
    short8 w1 = *(const short8*)(Wc1 + kc * 32);
    acc[0][0] = __builtin_amdgcn_mfma_f32_16x16x32_bf16(a0, w0, acc[0][0], 0, 0, 0);
    acc[0][1] = __builtin_amdgcn_mfma_f32_16x16x32_bf16(a0, w1, acc[0][1], 0, 0, 0);
    acc[1][0] = __builtin_amdgcn_mfma_f32_16x16x32_bf16(a1, w0, acc[1][0], 0, 0, 0);
    acc[1][1] = __builtin_amdgcn_mfma_f32_16x16x32_bf16(a1, w1, acc[1][1], 0, 0, 0);
  }
#pragma unroll
  for (int kc = 0; kc < 4; ++kc) {     // self half: k 128..255
    short8 a0 = *(const short8*)(selfA0 + kc * 32);
    short8 a1 = *(const short8*)(selfA1 + kc * 32);
    short8 w0 = *(const short8*)(Wc0 + 128 + kc * 32);
    short8 w1 = *(const short8*)(Wc1 + 128 + kc * 32);
    acc[0][0] = __builtin_amdgcn_mfma_f32_16x16x32_bf16(a0, w0, acc[0][0], 0, 0, 0);
    acc[0][1] = __builtin_amdgcn_mfma_f32_16x16x32_bf16(a0, w1, acc[0][1], 0, 0, 0);
    acc[1][0] = __builtin_amdgcn_mfma_f32_16x16x32_bf16(a1, w0, acc[1][0], 0, 0, 0);
    acc[1][1] = __builtin_amdgcn_mfma_f32_16x16x32_bf16(a1, w1, acc[1][1], 0, 0, 0);
  }

  float bv0 = b2[cw + m], bv1 = b2[cw + 16 + m];
#pragma unroll
  for (int rt = 0; rt < 2; ++rt) {
#pragma unroll
    for (int j = 0; j < 4; ++j) {
      int row = node0 + rw + rt * 16 + q * 4 + j;
      if (row < n) {
        float v0 = acc[rt][0][j] + bv0; v0 = v0 > 0.f ? v0 : 0.f;
        float v1 = acc[rt][1][j] + bv1; v1 = v1 > 0.f ? v1 : 0.f;
        out[(size_t)row * 128 + cw + m] = v0;
        out[(size_t)row * 128 + cw + 16 + m] = v1;
      }
    }
  }
}

// ---------------- launch ----------------

extern "C" void kernel_launch(void* const* d_in, const int* in_sizes, int n_in,
                              void* d_out, int out_size, void* d_ws, size_t ws_size,
                              hipStream_t stream) {
  const int N = N_NODES;
  const int E = in_sizes[1] / 2;
  const float* x   = (const float*)d_in[0];
  const int*   src = (const int*)d_in[1];
  const int*   dst = src + E;
  const float* Wl1 = (const float*)d_in[2];
  const float* Wr1 = (const float*)d_in[3];
  const float* b1  = (const float*)d_in[4];
  const float* Wl2 = (const float*)d_in[5];
  const float* Wr2 = (const float*)d_in[6];
  const float* b2  = (const float*)d_in[7];
  float* out = (float*)d_out;

  // workspace (~36 MB)
  unsigned short* xb = (unsigned short*)d_ws;         // N*64 bf16 (x cast)
  unsigned short* h1 = xb + (size_t)N * 64;           // N*128 bf16 (layer-1 out)
  unsigned short* W1 = h1 + (size_t)N * 128;          // 128*128
  unsigned short* W2 = W1 + 128 * 128;                // 128*256
  int* row_start  = (int*)(W2 + 128 * 256);           // N
  int* row_cnt    = row_start + N;                    // N
  int* bucket_cur = row_cnt + N;                      // NBUCK (padded to 784)
  int* buf        = bucket_cur + 784;                 // NBUCK*BCAP ints (6.4 MB)
  unsigned char* xq  = (unsigned char*)(buf + (size_t)NBUCK * BCAP);  // (N+1)*64 fp8
  unsigned char* h1q = xq + ((size_t)N + 1) * 64;                     // (N+1)*128 fp8

  (void)hipMemsetAsync(bucket_cur, 0, NBUCK * sizeof(int), stream);
  const int sb = 1024;                                // 2 blocks/CU for K1
  const int chunk = (E + sb - 1) / sb;                // 782 edges/block
  prep_scatter<<<sb, 512, 0, stream>>>(x, Wl1, Wr1, Wl2, Wr2, xb, xq, W1, W2,
                                       src, dst, bucket_cur, buf, chunk, E, N);
  csr_agg_gemm1<<<NBUCK, 512, 0, stream>>>(buf, bucket_cur, row_start, row_cnt,
                                           xb, xq, W1, b1, h1, h1q, N);
  agg_gemm2<<<NBUCK, 512, 0, stream>>>(h1, h1q, row_start, row_cnt, buf, W2, b2, out, N);
}

// Round 14
// 181.955 us; speedup vs baseline: 2.0072x; 1.0993x over previous
//
#include <hip/hip_runtime.h>

#define N_NODES 50000
#define NBUCK 782        // ceil(N_NODES / 64) -- 64 dst-nodes per bucket
#define BCAP 2048        // slots per bucket (mean fill 1024 + pad <=448)
#define BSHIFT 11

typedef __attribute__((ext_vector_type(8))) short short8;
typedef __attribute__((ext_vector_type(4))) float floatx4;
typedef __attribute__((ext_vector_type(2))) float floatx2;
typedef __attribute__((ext_vector_type(2))) int intx2;

static __device__ __forceinline__ unsigned short f2bf(float f) {
  unsigned int u = __builtin_bit_cast(unsigned int, f);
  u += 0x7fff + ((u >> 16) & 1);          // RNE
  return (unsigned short)(u >> 16);
}
// decode 8 fp8(e4m3) packed in int2 -> accumulate into 4x floatx2 (v_pk_add_f32)
static __device__ __forceinline__ void fp8x8_acc(intx2 v, floatx2* ac) {
  ac[0] += __builtin_amdgcn_cvt_pk_f32_fp8(v[0], false);
  ac[1] += __builtin_amdgcn_cvt_pk_f32_fp8(v[0], true);
  ac[2] += __builtin_amdgcn_cvt_pk_f32_fp8(v[1], false);
  ac[3] += __builtin_amdgcn_cvt_pk_f32_fp8(v[1], true);
}

// ---------------- K1: prep (casts incl. fp8 copy + zero sentinel rows) + bucket scatter ----------------

__global__ void __launch_bounds__(512) prep_scatter(
    const float* __restrict__ x,
    const float* __restrict__ Wl1, const float* __restrict__ Wr1,
    const float* __restrict__ Wl2, const float* __restrict__ Wr2,
    unsigned short* __restrict__ xb, unsigned char* __restrict__ xq,
    unsigned short* __restrict__ W1, unsigned short* __restrict__ W2,
    const int* __restrict__ src, const int* __restrict__ dst,
    int* __restrict__ bucket_cur, int* __restrict__ buf, int E, int n) {
  const int t = threadIdx.x;
  const int gid = blockIdx.x * 512 + t;
  const int gsz = gridDim.x * 512;
  for (int i = gid; i < n * 16; i += gsz) {       // 4 elems per iter
    float4 v = ((const float4*)x)[i];
    unsigned int lo = (unsigned int)f2bf(v.x) | ((unsigned int)f2bf(v.y) << 16);
    unsigned int hi = (unsigned int)f2bf(v.z) | ((unsigned int)f2bf(v.w) << 16);
    ((uint2*)xb)[i] = make_uint2(lo, hi);
    int q = __builtin_amdgcn_cvt_pk_fp8_f32(v.x, v.y, 0, false);
    q = __builtin_amdgcn_cvt_pk_fp8_f32(v.z, v.w, q, true);
    ((int*)xq)[i] = q;
  }
  // zero sentinel rows (index n): xq row n (64 B), h1q row n (128 B)
  {
    unsigned char* h1q = xq + ((size_t)n + 1) * 64;
    if (gid < 16) ((int*)(xq + (size_t)n * 64))[gid] = 0;
    if (gid >= 16 && gid < 48) ((int*)(h1q + (size_t)n * 128))[gid - 16] = 0;
  }
  for (int i = gid; i < 128 * 128; i += gsz) {
    int c = i >> 7, k = i & 127;
    W1[i] = f2bf(k < 64 ? Wl1[c * 64 + k] : Wr1[c * 64 + k - 64]);
  }
  for (int i = gid; i < 128 * 256; i += gsz) {
    int c = i >> 8, k = i & 255;
    W2[i] = f2bf(k < 128 ? Wl2[c * 128 + k] : Wr2[c * 128 + k - 128]);
  }

  // scatter: block handles chunk of 4096 edges; packed = (src<<6)|(dst&63)
  __shared__ int hist[NBUCK];
  __shared__ int base_s[NBUCK];
  for (int i = t; i < NBUCK; i += 512) hist[i] = 0;
  __syncthreads();
  int e0 = blockIdx.x * 4096;
  int sv[8], dv[8], bv[8];
#pragma unroll
  for (int p = 0; p < 8; ++p) {
    int e = e0 + p * 512 + t;
    if (e < E) {
      sv[p] = src[e];
      dv[p] = dst[e];
      bv[p] = dv[p] >> 6;
      atomicAdd(&hist[bv[p]], 1);
    } else bv[p] = -1;
  }
  __syncthreads();
  for (int i = t; i < NBUCK; i += 512) {
    int c = hist[i];
    base_s[i] = c > 0 ? atomicAdd(&bucket_cur[i], c) : 0;
  }
  __syncthreads();
  for (int i = t; i < NBUCK; i += 512) hist[i] = 0;   // reuse as sub-cursor
  __syncthreads();
#pragma unroll
  for (int p = 0; p < 8; ++p) {
    if (bv[p] >= 0) {
      int sub = base_s[bv[p]] + atomicAdd(&hist[bv[p]], 1);
      if (sub < BCAP) buf[(bv[p] << BSHIFT) + sub] = (sv[p] << 6) | (dv[p] & 63);
    }
  }
}

// ---------------- K2: bucket CSR (padded) + fp8 agg64 (2-deep prefetch) + layer-1 MFMA GEMM ----------------

__global__ void __launch_bounds__(512, 6) csr_agg_gemm1(
    int* __restrict__ buf, const int* __restrict__ bucket_cur,
    int* __restrict__ row_start, int* __restrict__ row_cnt,
    const unsigned short* __restrict__ xb, const unsigned char* __restrict__ xq,
    const unsigned short* __restrict__ W1, const float* __restrict__ b1,
    unsigned short* __restrict__ h1, unsigned char* __restrict__ h1q, int n) {
  __shared__ int eb[BCAP];                            // 8 KB staged packed edges
  __shared__ int gsrc[BCAP];                          // 8 KB grouped src lists
  __shared__ __align__(16) unsigned short aggS[64 * 72];  // 9 KB agg tile
  __shared__ int cnt[64];
  __shared__ int tmp[64];
  __shared__ int cur[64];
  const int t = threadIdx.x;
  const int b = blockIdx.x;
  const int node0 = b << 6;
  const int len = min(bucket_cur[b], BCAP);
  int* reg = buf + (b << BSHIFT);

  // --- CSR build (prefix over counts padded to multiple of 8) ---
  if (t < 64) cnt[t] = 0;
  __syncthreads();
  for (int i = t; i < len; i += 512) {
    int p = reg[i];
    eb[i] = p;
    atomicAdd(&cnt[p & 63], 1);
  }
  __syncthreads();
  if (t < 64) tmp[t] = (cnt[t] + 7) & ~7;
  __syncthreads();
#pragma unroll
  for (int off = 1; off < 64; off <<= 1) {
    int u = (t >= off && t < 64) ? tmp[t - off] : 0;
    __syncthreads();
    if (t < 64) tmp[t] += u;
    __syncthreads();
  }
  if (t < 64) {
    int c8 = (cnt[t] + 7) & ~7;
    int ex = tmp[t] - c8;
    cur[t] = ex;
    int nd = node0 + t;
    if (nd < n) {
      row_start[nd] = (b << BSHIFT) + ex;
      row_cnt[nd] = cnt[t];
    }
  }
  __syncthreads();
  for (int i = t; i < len; i += 512) {
    int p = eb[i];
    int sub = atomicAdd(&cur[p & 63], 1);
    int s = p >> 6;
    if (sub < BCAP) { gsrc[sub] = s; reg[sub] = s; }   // LDS + global copies
  }
  __syncthreads();
  if (t < 64) {                       // pad tail of each list with sentinel n
    int c8 = (cnt[t] + 7) & ~7;
    int e1 = tmp[t];
    for (int j = e1 - c8 + cnt[t]; j < e1; ++j)
      if (j < BCAP) { gsrc[j] = n; reg[j] = n; }
  }
  __syncthreads();

  // --- fp8 agg64: 8 waves, 2 nodes each, 2-deep prefetch (16 edges/node in flight) ---
  const int lane = t & 63;
  const int wv = t >> 6;
  const int eq = lane >> 3;            // edge slot 0..7
  const int cl = lane & 7;             // 8-B chunk: cols cl*8..cl*8+7
#pragma unroll 1
  for (int p = 0; p < 4; ++p) {
    int locA = wv + p * 16;
    int locB = locA + 8;
    int cnA = cnt[locA], cnB = cnt[locB];
    int cpA = (cnA + 7) & ~7, cpB = (cnB + 7) & ~7;
    int baseA = tmp[locA] - cpA;
    int baseB = tmp[locB] - cpB;
    floatx2 aA[4], aB[4];
#pragma unroll
    for (int j = 0; j < 4; ++j) { aA[j] = (floatx2){0.f, 0.f}; aB[j] = (floatx2){0.f, 0.f}; }
    int mx = max(cpA, cpB);
    int sA = (0 < cpA) ? gsrc[baseA + eq] : n;
    int sB = (0 < cpB) ? gsrc[baseB + eq] : n;
    int sA1 = (8 < cpA) ? gsrc[baseA + 8 + eq] : n;
    int sB1 = (8 < cpB) ? gsrc[baseB + 8 + eq] : n;
    intx2 vA = *(const intx2*)(xq + (size_t)sA * 64 + cl * 8);
    intx2 vB = *(const intx2*)(xq + (size_t)sB * 64 + cl * 8);
    intx2 uA = *(const intx2*)(xq + (size_t)sA1 * 64 + cl * 8);
    intx2 uB = *(const intx2*)(xq + (size_t)sB1 * 64 + cl * 8);
    for (int e = 16; e < mx; e += 8) {
      int nA = (e < cpA) ? gsrc[baseA + e + eq] : n;
      int nB = (e < cpB) ? gsrc[baseB + e + eq] : n;
      intx2 wA = *(const intx2*)(xq + (size_t)nA * 64 + cl * 8);
      intx2 wB = *(const intx2*)(xq + (size_t)nB * 64 + cl * 8);
      fp8x8_acc(vA, aA);
      fp8x8_acc(vB, aB);
      vA = uA; vB = uB; uA = wA; uB = wB;
    }
    fp8x8_acc(vA, aA);
    fp8x8_acc(vB, aB);
    fp8x8_acc(uA, aA);
    fp8x8_acc(uB, aB);
    float rA[8], rB[8];
#pragma unroll
    for (int j = 0; j < 4; ++j) {
      rA[2 * j] = aA[j][0]; rA[2 * j + 1] = aA[j][1];
      rB[2 * j] = aB[j][0]; rB[2 * j + 1] = aB[j][1];
    }
#pragma unroll
    for (int j = 0; j < 8; ++j) {
      rA[j] += __shfl_xor(rA[j], 8, 64);
      rA[j] += __shfl_xor(rA[j], 16, 64);
      rA[j] += __shfl_xor(rA[j], 32, 64);
      rB[j] += __shfl_xor(rB[j], 8, 64);
      rB[j] += __shfl_xor(rB[j], 16, 64);
      rB[j] += __shfl_xor(rB[j], 32, 64);
    }
    if (eq == 0) {
      float invA = 1.0f / (float)max(cnA, 1);
      float invB = 1.0f / (float)max(cnB, 1);
      short8 oA, oB;
#pragma unroll
      for (int j = 0; j < 8; ++j) { oA[j] = (short)f2bf(rA[j] * invA); oB[j] = (short)f2bf(rB[j] * invB); }
      *(short8*)(aggS + locA * 72 + cl * 8) = oA;
      *(short8*)(aggS + locB * 72 + cl * 8) = oB;
    }
  }
  __syncthreads();

  // --- MFMA gemm1: 8 waves = 2 row-tiles x 4 col-tiles of 32x32; K=128 ---
  const int m = lane & 15;
  const int q = lane >> 4;
  const int rw = (wv & 1) * 32;
  const int cw = (wv >> 1) * 32;
  floatx4 acc[2][2];
#pragma unroll
  for (int rt = 0; rt < 2; ++rt)
#pragma unroll
    for (int ct = 0; ct < 2; ++ct) acc[rt][ct] = (floatx4){0.f, 0.f, 0.f, 0.f};

  int ra = node0 + rw + m;      if (ra > n - 1) ra = n - 1;
  int rb = node0 + rw + 16 + m; if (rb > n - 1) rb = n - 1;
  const unsigned short* selfA0 = xb + (size_t)ra * 64 + q * 8;
  const unsigned short* selfA1 = xb + (size_t)rb * 64 + q * 8;
  const unsigned short* aggL0 = aggS + (rw + m) * 72 + q * 8;
  const unsigned short* aggL1 = aggS + (rw + 16 + m) * 72 + q * 8;
  const unsigned short* Wc0 = W1 + (size_t)(cw + m) * 128 + q * 8;
  const unsigned short* Wc1 = W1 + (size_t)(cw + 16 + m) * 128 + q * 8;

#pragma unroll
  for (int kc = 0; kc < 2; ++kc) {     // agg half: k 0..63
    short8 a0 = *(const short8*)(aggL0 + kc * 32);
    short8 a1 = *(const short8*)(aggL1 + kc * 32);
    short8 w0 = *(const short8*)(Wc0 + kc * 32);
    short8 w1 = *(const short8*)(Wc1 + kc * 32);
    acc[0][0] = __builtin_amdgcn_mfma_f32_16x16x32_bf16(a0, w0, acc[0][0], 0, 0, 0);
    acc[0][1] = __builtin_amdgcn_mfma_f32_16x16x32_bf16(a0, w1, acc[0][1], 0, 0, 0);
    acc[1][0] = __builtin_amdgcn_mfma_f32_16x16x32_bf16(a1, w0, acc[1][0], 0, 0, 0);
    acc[1][1] = __builtin_amdgcn_mfma_f32_16x16x32_bf16(a1, w1, acc[1][1], 0, 0, 0);
  }
#pragma unroll
  for (int kc = 0; kc < 2; ++kc) {     // self half: k 64..127
    short8 a0 = *(const short8*)(selfA0 + kc * 32);
    short8 a1 = *(const short8*)(selfA1 + kc * 32);
    short8 w0 = *(const short8*)(Wc0 + 64 + kc * 32);
    short8 w1 = *(const short8*)(Wc1 + 64 + kc * 32);
    acc[0][0] = __builtin_amdgcn_mfma_f32_16x16x32_bf16(a0, w0, acc[0][0], 0, 0, 0);
    acc[0][1] = __builtin_amdgcn_mfma_f32_16x16x32_bf16(a0, w1, acc[0][1], 0, 0, 0);
    acc[1][0] = __builtin_amdgcn_mfma_f32_16x16x32_bf16(a1, w0, acc[1][0], 0, 0, 0);
    acc[1][1] = __builtin_amdgcn_mfma_f32_16x16x32_bf16(a1, w1, acc[1][1], 0, 0, 0);
  }

  float bv0 = b1[cw + m], bv1 = b1[cw + 16 + m];
#pragma unroll
  for (int rt = 0; rt < 2; ++rt) {
#pragma unroll
    for (int j = 0; j < 4; ++j) {
      int row = node0 + rw + rt * 16 + q * 4 + j;
      if (row < n) {
        float v0 = acc[rt][0][j] + bv0; v0 = v0 > 0.f ? v0 : 0.f;
        float v1 = acc[rt][1][j] + bv1; v1 = v1 > 0.f ? v1 : 0.f;
        h1[(size_t)row * 128 + cw + m] = f2bf(v0);
        h1[(size_t)row * 128 + cw + 16 + m] = f2bf(v1);
        h1q[(size_t)row * 128 + cw + m] =
            (unsigned char)__builtin_amdgcn_cvt_pk_fp8_f32(v0, v0, 0, false);
        h1q[(size_t)row * 128 + cw + 16 + m] =
            (unsigned char)__builtin_amdgcn_cvt_pk_fp8_f32(v1, v1, 0, false);
      }
    }
  }
}

// ---------------- K3: fp8 agg128 (LDS metadata + 2-deep prefetch) + layer-2 MFMA GEMM ----------------

__global__ void __launch_bounds__(512, 6) agg_gemm2(
    const unsigned short* __restrict__ h1, const unsigned char* __restrict__ h1q,
    const int* __restrict__ row_start, const int* __restrict__ row_cnt,
    const int* __restrict__ buf, const unsigned short* __restrict__ W2,
    const float* __restrict__ b2, float* __restrict__ out, int n) {
  __shared__ int gsrcS[BCAP];                             // 8 KB staged indices
  __shared__ __align__(16) unsigned short aggS[64 * 136]; // 17 KB (pad 128->136)
  __shared__ int cntS[64];
  __shared__ int stS[64];
  const int t = threadIdx.x;
  const int lane = t & 63;
  const int wv = t >> 6;
  const int node0 = blockIdx.x << 6;
  const int boff = blockIdx.x << BSHIFT;

  {
    const int4* b4 = (const int4*)(buf + ((size_t)blockIdx.x << BSHIFT));
    ((int4*)gsrcS)[t] = b4[t];
  }
  if (t < 64) {
    int nd = node0 + t;
    cntS[t] = (nd < n) ? row_cnt[nd] : 0;
    stS[t]  = (nd < n) ? (row_start[nd] - boff) : 0;
  }
  __syncthreads();

  const int eq = lane >> 4;            // edge slot 0..3
  const int cl = lane & 15;            // 8-B chunk: cols cl*8..cl*8+7
#pragma unroll 1
  for (int lp = 0; lp < 4; ++lp) {
    int locA = wv + lp * 16;
    int locB = locA + 8;
    int cnA = cntS[locA], stA = stS[locA];
    int cnB = cntS[locB], stB = stS[locB];
    int cpA = (cnA + 7) & ~7, cpB = (cnB + 7) & ~7;
    int mx = max(cpA, cpB);
    floatx2 aA[4], aB[4];
#pragma unroll
    for (int j = 0; j < 4; ++j) { aA[j] = (floatx2){0.f, 0.f}; aB[j] = (floatx2){0.f, 0.f}; }
    int iA0 = (0 < cpA) ? gsrcS[stA + eq] : n;
    int iA1 = (0 < cpA) ? gsrcS[stA + 4 + eq] : n;
    int iB0 = (0 < cpB) ? gsrcS[stB + eq] : n;
    int iB1 = (0 < cpB) ? gsrcS[stB + 4 + eq] : n;
    intx2 vA0 = *(const intx2*)(h1q + (size_t)iA0 * 128 + cl * 8);
    intx2 vA1 = *(const intx2*)(h1q + (size_t)iA1 * 128 + cl * 8);
    intx2 vB0 = *(const intx2*)(h1q + (size_t)iB0 * 128 + cl * 8);
    intx2 vB1 = *(const intx2*)(h1q + (size_t)iB1 * 128 + cl * 8);
    int jA0 = (8 < cpA) ? gsrcS[stA + 8 + eq] : n;
    int jA1 = (8 < cpA) ? gsrcS[stA + 12 + eq] : n;
    int jB0 = (8 < cpB) ? gsrcS[stB + 8 + eq] : n;
    int jB1 = (8 < cpB) ? gsrcS[stB + 12 + eq] : n;
    intx2 uA0 = *(const intx2*)(h1q + (size_t)jA0 * 128 + cl * 8);
    intx2 uA1 = *(const intx2*)(h1q + (size_t)jA1 * 128 + cl * 8);
    intx2 uB0 = *(const intx2*)(h1q + (size_t)jB0 * 128 + cl * 8);
    intx2 uB1 = *(const intx2*)(h1q + (size_t)jB1 * 128 + cl * 8);
    for (int e = 16; e < mx; e += 8) {
      int kA0 = (e < cpA) ? gsrcS[stA + e + eq] : n;
      int kA1 = (e < cpA) ? gsrcS[stA + e + 4 + eq] : n;
      int kB0 = (e < cpB) ? gsrcS[stB + e + eq] : n;
      int kB1 = (e < cpB) ? gsrcS[stB + e + 4 + eq] : n;
      intx2 wA0 = *(const intx2*)(h1q + (size_t)kA0 * 128 + cl * 8);
      intx2 wA1 = *(const intx2*)(h1q + (size_t)kA1 * 128 + cl * 8);
      intx2 wB0 = *(const intx2*)(h1q + (size_t)kB0 * 128 + cl * 8);
      intx2 wB1 = *(const intx2*)(h1q + (size_t)kB1 * 128 + cl * 8);
      fp8x8_acc(vA0, aA); fp8x8_acc(vA1, aA);
      fp8x8_acc(vB0, aB); fp8x8_acc(vB1, aB);
      vA0 = uA0; vA1 = uA1; vB0 = uB0; vB1 = uB1;
      uA0 = wA0; uA1 = wA1; uB0 = wB0; uB1 = wB1;
    }
    fp8x8_acc(vA0, aA); fp8x8_acc(vA1, aA);
    fp8x8_acc(vB0, aB); fp8x8_acc(vB1, aB);
    fp8x8_acc(uA0, aA); fp8x8_acc(uA1, aA);
    fp8x8_acc(uB0, aB); fp8x8_acc(uB1, aB);

    float rA[8], rB[8];
#pragma unroll
    for (int j = 0; j < 4; ++j) {
      rA[2 * j] = aA[j][0]; rA[2 * j + 1] = aA[j][1];
      rB[2 * j] = aB[j][0]; rB[2 * j + 1] = aB[j][1];
    }
#pragma unroll
    for (int j = 0; j < 8; ++j) {
      rA[j] += __shfl_xor(rA[j], 16, 64);
      rA[j] += __shfl_xor(rA[j], 32, 64);
      rB[j] += __shfl_xor(rB[j], 16, 64);
      rB[j] += __shfl_xor(rB[j], 32, 64);
    }
    if (eq == 0) {
      float invA = 1.0f / (float)max(cnA, 1);
      float invB = 1.0f / (float)max(cnB, 1);
      short8 oA, oB;
#pragma unroll
      for (int j = 0; j < 8; ++j) { oA[j] = (short)f2bf(rA[j] * invA); oB[j] = (short)f2bf(rB[j] * invB); }
      *(short8*)(aggS + locA * 136 + cl * 8) = oA;
      *(short8*)(aggS + locB * 136 + cl * 8) = oB;
    }
  }
  __syncthreads();

  // --- MFMA gemm2: 8 waves = 2 row-tiles x 4 col-tiles of 32x32; K=256 ---
  const int m = lane & 15;
  const int q = lane >> 4;
  const int rw = (wv & 1) * 32;
  const int cw = (wv >> 1) * 32;
  floatx4 acc[2][2];
#pragma unroll
  for (int rt = 0; rt < 2; ++rt)
#pragma unroll
    for (int ct = 0; ct < 2; ++ct) acc[rt][ct] = (floatx4){0.f, 0.f, 0.f, 0.f};

  int ra = node0 + rw + m;      if (ra > n - 1) ra = n - 1;
  int rb = node0 + rw + 16 + m; if (rb > n - 1) rb = n - 1;
  const unsigned short* selfA0 = h1 + (size_t)ra * 128 + q * 8;
  const unsigned short* selfA1 = h1 + (size_t)rb * 128 + q * 8;
  const unsigned short* aggL0 = aggS + (rw + m) * 136 + q * 8;
  const unsigned short* aggL1 = aggS + (rw + 16 + m) * 136 + q * 8;
  const unsigned short* Wc0 = W2 + (size_t)(cw + m) * 256 + q * 8;
  const unsigned short* Wc1 = W2 + (size_t)(cw + 16 + m) * 256 + q * 8;

#pragma unroll
  for (int kc = 0; kc < 4; ++kc) {     // agg half: k 0..127
    short8 a0 = *(const short8*)(aggL0 + kc * 32);
    short8 a1 = *(const short8*)(aggL1 + kc * 32);
    short8 w0 = *(const short8*)(Wc0 + kc * 32);
    short8 w1 = *(const short8*)(Wc1 + kc * 32);
    acc[0][0] = __builtin_amdgcn_mfma_f32_16x16x32_bf16(a0, w0, acc[0][0], 0, 0, 0);
    acc[0][1] = __builtin_amdgcn_mfma_f32_16x16x32_bf16(a0, w1, acc[0][1], 0, 0, 0);
    acc[1][0] = __builtin_amdgcn_mfma_f32_16x16x32_bf16(a1, w0, acc[1][0], 0, 0, 0);
    acc[1][1] = __builtin_amdgcn_mfma_f32_16x16x32_bf16(a1, w1, acc[1][1], 0, 0, 0);
  }
#pragma unroll
  for (int kc = 0; kc < 4; ++kc) {     // self half: k 128..255
    short8 a0 = *(const short8*)(selfA0 + kc * 32);
    short8 a1 = *(const short8*)(selfA1 + kc * 32);
    short8 w0 = *(const short8*)(Wc0 + 128 + kc * 32);
    short8 w1 = *(const short8*)(Wc1 + 128 + kc * 32);
    acc[0][0] = __builtin_amdgcn_mfma_f32_16x16x32_bf16(a0, w0, acc[0][0], 0, 0, 0);
    acc[0][1] = __builtin_amdgcn_mfma_f32_16x16x32_bf16(a0, w1, acc[0][1], 0, 0, 0);
    acc[1][0] = __builtin_amdgcn_mfma_f32_16x16x32_bf16(a1, w0, acc[1][0], 0, 0, 0);
    acc[1][1] = __builtin_amdgcn_mfma_f32_16x16x32_bf16(a1, w1, acc[1][1], 0, 0, 0);
  }

  float bv0 = b2[cw + m], bv1 = b2[cw + 16 + m];
#pragma unroll
  for (int rt = 0; rt < 2; ++rt) {
#pragma unroll
    for (int j = 0; j < 4; ++j) {
      int row = node0 + rw + rt * 16 + q * 4 + j;
      if (row < n) {
        float v0 = acc[rt][0][j] + bv0; v0 = v0 > 0.f ? v0 : 0.f;
        float v1 = acc[rt][1][j] + bv1; v1 = v1 > 0.f ? v1 : 0.f;
        out[(size_t)row * 128 + cw + m] = v0;
        out[(size_t)row * 128 + cw + 16 + m] = v1;
      }
    }
  }
}

// ---------------- launch ----------------

extern "C" void kernel_launch(void* const* d_in, const int* in_sizes, int n_in,
                              void* d_out, int out_size, void* d_ws, size_t ws_size,
                              hipStream_t stream) {
  const int N = N_NODES;
  const int E = in_sizes[1] / 2;
  const float* x   = (const float*)d_in[0];
  const int*   src = (const int*)d_in[1];
  const int*   dst = src + E;
  const float* Wl1 = (const float*)d_in[2];
  const float* Wr1 = (const float*)d_in[3];
  const float* b1  = (const float*)d_in[4];
  const float* Wl2 = (const float*)d_in[5];
  const float* Wr2 = (const float*)d_in[6];
  const float* b2  = (const float*)d_in[7];
  float* out = (float*)d_out;

  // workspace (~36 MB)
  unsigned short* xb = (unsigned short*)d_ws;         // N*64 bf16 (x cast)
  unsigned short* h1 = xb + (size_t)N * 64;           // N*128 bf16 (layer-1 out)
  unsigned short* W1 = h1 + (size_t)N * 128;          // 128*128
  unsigned short* W2 = W1 + 128 * 128;                // 128*256
  int* row_start  = (int*)(W2 + 128 * 256);           // N
  int* row_cnt    = row_start + N;                    // N
  int* bucket_cur = row_cnt + N;                      // NBUCK (padded to 784)
  int* buf        = bucket_cur + 784;                 // NBUCK*BCAP ints (6.4 MB)
  unsigned char* xq  = (unsigned char*)(buf + (size_t)NBUCK * BCAP);  // (N+1)*64 fp8
  unsigned char* h1q = xq + ((size_t)N + 1) * 64;                     // (N+1)*128 fp8

  (void)hipMemsetAsync(bucket_cur, 0, NBUCK * sizeof(int), stream);
  int sb = (E + 4095) / 4096;                         // 196 blocks
  prep_scatter<<<sb, 512, 0, stream>>>(x, Wl1, Wr1, Wl2, Wr2, xb, xq, W1, W2,
                                       src, dst, bucket_cur, buf, E, N);
  csr_agg_gemm1<<<NBUCK, 512, 0, stream>>>(buf, bucket_cur, row_start, row_cnt,
                                           xb, xq, W1, b1, h1, h1q, N);
  agg_gemm2<<<NBUCK, 512, 0, stream>>>(h1, h1q, row_start, row_cnt, buf, W2, b2, out, N);
}